// Round 1
// baseline (1047.404 us; speedup 1.0000x reference)
//
#include <hip/hip_runtime.h>
#include <stdint.h>

// ----------------------------------------------------------------------------
// HebbianLayer on MI355X (gfx950).
// B=8, T=4096, D=768, d_inner=1536, reference CHUNK=64.
// R3: scan re-chunked to C=1024 -> 3 parallel GEMM kernels (wstate/pmat/reads).
// R4: conv rewritten as sliding-window streaming kernel.
// R5: dense GEMMs (pg, out_proj, write, final) moved to an 8-phase 256x256
// double-buffered engine (counted vmcnt(4), never drained in-loop; per-phase
// {ds_read || 1 half-tile global_load_lds stage -> barrier -> lgkmcnt(0) ->
// 16 MFMA -> barrier}). wstate/pmat/reads unchanged this round.
// ----------------------------------------------------------------------------

typedef short bf16s;                                            // raw bf16 bits
typedef __attribute__((ext_vector_type(8))) short short8;       // 4 VGPR mfma frag
typedef __attribute__((ext_vector_type(4))) float f32x4;        // mfma acc

#define DEVINL __device__ __forceinline__

DEVINL float bf2f(short s) {
    union { unsigned u; float f; } v; v.u = ((unsigned)(unsigned short)s) << 16; return v.f;
}
DEVINL short f2bf(float f) {
    union { float f; unsigned u; } v; v.f = f;
    unsigned r = v.u + 0x7fffu + ((v.u >> 16) & 1u);            // RNE
    return (short)(r >> 16);
}

// async global->LDS, 16B per lane. LDS dest must be wave-uniform.
DEVINL void glds16(void* lds, const void* g) {
    __builtin_amdgcn_global_load_lds(
        (const __attribute__((address_space(1))) void*)g,
        (__attribute__((address_space(3))) void*)lds, 16, 0, 0);
}

// Stage a 128-row x 64-col bf16 tile with 256 threads (4 waves). g must be
// pre-offset by sr*gstride + sf*8 where sr=tid>>3, sf=(tid&7)^(sr&7).
DEVINL void stage128(bf16s* lds, const bf16s* g, long gstride, int wave) {
#pragma unroll
    for (int p = 0; p < 4; ++p)
        glds16(lds + p * 2048 + wave * 512, g + (long)p * 32 * gstride);
}

// Same tile staged by 512 threads (8 waves): 2 x 16B per thread.
// sr=tid>>3 (0..63), sf=(tid&7)^(sr&7); covers rows sr and sr+64.
DEVINL void stage_half512(bf16s* lds, const bf16s* g, long gstride, int wave) {
#pragma unroll
    for (int p = 0; p < 2; ++p)
        glds16(lds + p * 4096 + wave * 512, g + (long)p * 64 * gstride);
}

// Read an A/B fragment from a swizzled 64-col tile.
DEVINL short8 fragr(const bf16s* t, int row, int kk, int q) {
    int f = kk * 4 + q;
    return *(const short8*)(t + row * 64 + ((f ^ (row & 7)) * 8));
}

#define MFMA(a, b, c) __builtin_amdgcn_mfma_f32_16x16x32_bf16((a), (b), (c), 0, 0, 0)

// ---------------------------------------------------------------------------
// K0: weight casts (fp32 -> bf16). w_pg = [proj_w ; gate_w] rows (3072x768).
// ---------------------------------------------------------------------------
__global__ __launch_bounds__(256) void cast_w_kernel(
    const float* __restrict__ proj, const float* __restrict__ gate,
    const float* __restrict__ op, const float* __restrict__ wr, const float* __restrict__ rd,
    bf16s* __restrict__ w_pg, bf16s* __restrict__ w_op, bf16s* __restrict__ w_wr,
    bf16s* __restrict__ w_rd) {
    long i = (long)blockIdx.x * 256 + threadIdx.x;
    if (i < 1179648)        w_pg[i] = f2bf(proj[i]);
    else if (i < 2359296)   w_pg[i] = f2bf(gate[i - 1179648]);
    else if (i < 3538944)   w_op[i - 2359296] = f2bf(op[i - 2359296]);
    else if (i < 4128768)   w_wr[i - 3538944] = f2bf(wr[i - 3538944]);
    else if (i < 4718592)   w_rd[i - 4128768] = f2bf(rd[i - 4128768]);
}

// ---------------------------------------------------------------------------
// K1: RMSNorm + cast. One block per row (768 elems).
// ---------------------------------------------------------------------------
__global__ __launch_bounds__(256) void rmsnorm_kernel(
    const float* __restrict__ x, const float* __restrict__ w, bf16s* __restrict__ xn) {
    long row = blockIdx.x;
    const float* xr = x + row * 768;
    int tid = threadIdx.x;
    float v0 = xr[tid], v1 = xr[tid + 256], v2 = xr[tid + 512];
    float ss = v0 * v0 + v1 * v1 + v2 * v2;
#pragma unroll
    for (int off = 32; off; off >>= 1) ss += __shfl_down(ss, off);
    __shared__ float p[4];
    if ((tid & 63) == 0) p[tid >> 6] = ss;
    __syncthreads();
    float tot = p[0] + p[1] + p[2] + p[3];
    float s = rsqrtf(tot * (1.0f / 768.0f) + 1e-5f);
    bf16s* o = xn + row * 768;
    o[tid]       = f2bf(v0 * s * w[tid]);
    o[tid + 256] = f2bf(v1 * s * w[tid + 256]);
    o[tid + 512] = f2bf(v2 * s * w[tid + 512]);
}

// ---------------------------------------------------------------------------
// GEMM8: C[M,N] = A[M,K] @ B[N,K]^T. 256x256 tile, BK=64, 8 waves (2Mx4N),
// 8-phase double-buffered schedule, counted vmcnt(4) at phases 4 and 8 only.
// Requires M%256==0, N%256==0, (K/64) even.
// MODE 0: store bf16.   MODE 1: d_out = x + bf2f(outres) + exp(la)*acc (f32).
//
// Stage placement (slotX.half <- K-tile), derived so each LDS region is only
// re-staged after its last ds_read completed at a prior barrier:
//   prologue: s0A0,s0A1,s0B0,s0B1 (t=0), s1A0,s1A1 (t=1); vmcnt(4)
//   P1: s1B0(2i+1)  P2: s1B1(2i+1)  P3: s0A0(2i+2)  P4: s0A1(2i+2) +vmcnt(4)
//   P5: s0B0(2i+2)  P6: s0B1(2i+2)  P7: s1A0(2i+3)  P8: s1A1(2i+3) +vmcnt(4)
// At each vmcnt(4): 12 loads outstanding, oldest 8 complete == the full slot
// needed by the next 4 phases.
// ---------------------------------------------------------------------------
#define P_MID()                                                   \
    asm volatile("" ::: "memory");                                \
    __builtin_amdgcn_s_barrier();                                 \
    asm volatile("s_waitcnt lgkmcnt(0)" ::: "memory");            \
    __builtin_amdgcn_sched_barrier(0);                            \
    __builtin_amdgcn_s_setprio(1)

#define P_END()                                                   \
    __builtin_amdgcn_s_setprio(0);                                \
    asm volatile("" ::: "memory");                                \
    __builtin_amdgcn_s_barrier();                                 \
    asm volatile("" ::: "memory")

#define P_END_VM()                                                \
    __builtin_amdgcn_s_setprio(0);                                \
    asm volatile("s_waitcnt vmcnt(4)" ::: "memory");              \
    asm volatile("" ::: "memory");                                \
    __builtin_amdgcn_s_barrier();                                 \
    asm volatile("" ::: "memory")

#define RD_A(dst, s, kk)                                          \
    _Pragma("unroll")                                             \
    for (int m = 0; m < 8; ++m) dst[m] = fragr(&sA[s][wm][0], m * 16 + ln15, kk, q)

#define RD_B(dst, s, kk)                                          \
    _Pragma("unroll")                                             \
    for (int n = 0; n < 4; ++n) dst[n] = fragr(&sB[s][bh][0], (wn & 1) * 64 + n * 16 + ln15, kk, q)

#define Q_MFMA(af, bfr, nlo)                                      \
    _Pragma("unroll")                                             \
    for (int m = 0; m < 8; ++m) {                                 \
        acc[m][nlo]     = MFMA(af[m], bfr[nlo],     acc[m][nlo]);     \
        acc[m][nlo + 1] = MFMA(af[m], bfr[nlo + 1], acc[m][nlo + 1]); \
    }

template <int MODE>
__global__ __launch_bounds__(512, 2) void gemm8_kernel(
    const bf16s* __restrict__ A, const bf16s* __restrict__ B, int K, int N,
    bf16s* __restrict__ Cb, const float* __restrict__ xres,
    const bf16s* __restrict__ outres, const float* __restrict__ p_la,
    float* __restrict__ Cout) {
    __shared__ bf16s sA[2][2][8192];     // [slot][half: M 0-127 / 128-255]
    __shared__ bf16s sB[2][2][8192];     // [slot][half: N 0-127 / 128-255]
    const int tid = threadIdx.x;
    const int wave = tid >> 6, lane = tid & 63;
    const int wm = wave >> 2, wn = wave & 3;     // 2 M-waves x 4 N-waves
    const int bh = wn >> 1;                      // which B half this wave reads
    const int ln15 = lane & 15, q = lane >> 4;
    const long m0 = (long)blockIdx.y * 256, n0 = (long)blockIdx.x * 256;
    const int sr = tid >> 3;                     // 0..63
    const int sf = (tid & 7) ^ (sr & 7);
    const bf16s* pA0 = A + (m0 + sr) * K + sf * 8;
    const bf16s* pA1 = A + (m0 + 128 + sr) * K + sf * 8;
    const bf16s* pB0 = B + (n0 + sr) * K + sf * 8;
    const bf16s* pB1 = B + (n0 + 128 + sr) * K + sf * 8;
    const int NKT = K >> 6, NI = NKT >> 1;

    // prologue
    stage_half512(&sA[0][0][0], pA0, K, wave);
    stage_half512(&sA[0][1][0], pA1, K, wave);
    stage_half512(&sB[0][0][0], pB0, K, wave);
    stage_half512(&sB[0][1][0], pB1, K, wave);
    stage_half512(&sA[1][0][0], pA0 + 64, K, wave);
    stage_half512(&sA[1][1][0], pA1 + 64, K, wave);
    asm volatile("s_waitcnt vmcnt(4)" ::: "memory");
    asm volatile("" ::: "memory");
    __builtin_amdgcn_s_barrier();
    asm volatile("" ::: "memory");

    f32x4 acc[8][4] = {};
    short8 a0[8], a1[8], b0[4], b1[4];

    for (int it = 0; it < NI; ++it) {
        const long o1 = (long)(2 * it + 1) * 64;
        int t2 = 2 * it + 2; if (t2 > NKT - 1) t2 = NKT - 1;   // clamped dummy
        int t3 = 2 * it + 3; if (t3 > NKT - 1) t3 = NKT - 1;   // (keeps vmcnt
        const long o2 = (long)t2 * 64, o3 = (long)t3 * 64;     //  counts exact)
        // ---- phases 1-4: compute K-tile 2it from slot 0 ----
        RD_A(a0, 0, 0); RD_B(b0, 0, 0);
        stage_half512(&sB[1][0][0], pB0 + o1, K, wave);
        P_MID(); Q_MFMA(a0, b0, 0); P_END();
        RD_A(a1, 0, 1);
        stage_half512(&sB[1][1][0], pB1 + o1, K, wave);
        P_MID(); Q_MFMA(a0, b0, 2); P_END();
        RD_B(b1, 0, 1);
        stage_half512(&sA[0][0][0], pA0 + o2, K, wave);
        P_MID(); Q_MFMA(a1, b1, 0); P_END();
        stage_half512(&sA[0][1][0], pA1 + o2, K, wave);
        P_MID(); Q_MFMA(a1, b1, 2); P_END_VM();
        // ---- phases 5-8: compute K-tile 2it+1 from slot 1 ----
        RD_A(a0, 1, 0); RD_B(b0, 1, 0);
        stage_half512(&sB[0][0][0], pB0 + o2, K, wave);
        P_MID(); Q_MFMA(a0, b0, 0); P_END();
        RD_A(a1, 1, 1);
        stage_half512(&sB[0][1][0], pB1 + o2, K, wave);
        P_MID(); Q_MFMA(a0, b0, 2); P_END();
        RD_B(b1, 1, 1);
        stage_half512(&sA[1][0][0], pA0 + o3, K, wave);
        P_MID(); Q_MFMA(a1, b1, 0); P_END();
        stage_half512(&sA[1][1][0], pA1 + o3, K, wave);
        P_MID(); Q_MFMA(a1, b1, 2); P_END_VM();
    }
    asm volatile("s_waitcnt vmcnt(0)" ::: "memory");

    float alpha = 0.f;
    if (MODE == 1) alpha = __expf(p_la[0]);
#pragma unroll
    for (int m = 0; m < 8; ++m)
#pragma unroll
        for (int n = 0; n < 4; ++n) {
            long mb = m0 + wm * 128 + m * 16 + q * 4;
            long nc = n0 + wn * 64 + n * 16 + ln15;
#pragma unroll
            for (int e = 0; e < 4; ++e) {
                long mm = mb + e;
                float v = acc[m][n][e];
                if (MODE == 0) {
                    Cb[mm * N + nc] = f2bf(v);
                } else {
                    long idx = mm * 768 + nc;
                    Cout[idx] = xres[idx] + bf2f(outres[idx]) + alpha * v;
                }
            }
        }
}

// ---------------------------------------------------------------------------
// K3: depthwise causal conv(4) + bias + SiLU, gated by SiLU(gate).
// Sliding-window streaming version: thread owns 8 channels x 16 time steps.
// ---------------------------------------------------------------------------
__global__ __launch_bounds__(192) void conv_kernel(
    const bf16s* __restrict__ pg, const float* __restrict__ cw,
    const float* __restrict__ cb, bf16s* __restrict__ vg) {
    const int e0 = threadIdx.x * 8;
    const long l0 = (long)blockIdx.x * 16;
    float w0[8], w1[8], w2[8], w3[8], bias[8];
#pragma unroll
    for (int i = 0; i < 8; ++i) {
        const float* wc = cw + (e0 + i) * 4;
        w0[i] = wc[0]; w1[i] = wc[1]; w2[i] = wc[2]; w3[i] = wc[3];
        bias[i] = cb[e0 + i];
    }
    const bf16s* base = pg + l0 * 3072 + e0;
    short8 h0, h1, h2;
    if ((l0 & 4095) == 0) {
        short8 z = {0, 0, 0, 0, 0, 0, 0, 0};
        h0 = z; h1 = z; h2 = z;
    } else {
        h0 = *(const short8*)(base - 3 * 3072);
        h1 = *(const short8*)(base - 2 * 3072);
        h2 = *(const short8*)(base - 1 * 3072);
    }
    short8 cur = *(const short8*)base;
    short8 g8  = *(const short8*)(base + 1536);
    bf16s* out = vg + l0 * 1536 + e0;
#pragma unroll 4
    for (int t = 0; t < 16; ++t) {
        short8 ncur, ng;
        if (t < 15) {                       // prefetch next row
            ncur = *(const short8*)(base + 3072);
            ng   = *(const short8*)(base + 3072 + 1536);
        }
        short8 o;
#pragma unroll
        for (int i = 0; i < 8; ++i) {
            float vv = bias[i] + bf2f(h0[i]) * w0[i] + bf2f(h1[i]) * w1[i]
                     + bf2f(h2[i]) * w2[i] + bf2f(cur[i]) * w3[i];
            float sv = vv / (1.0f + __expf(-vv));
            float gg = bf2f(g8[i]);
            o[i] = f2bf(sv * (gg / (1.0f + __expf(-gg))));
        }
        *(short8*)out = o;
        h0 = h1; h1 = h2; h2 = cur;
        cur = ncur; g8 = ng;
        base += 3072; out += 1536;
    }
}

// ---------------------------------------------------------------------------
// K5: transpose [b][t][e] -> [b][e][t], optional shift (t -> t-1, zero fill)
// and optional gw scale gamma^(1023 - t%1024). bf16 -> bf16.
// ---------------------------------------------------------------------------
template <int SHIFT, int GW>
__global__ __launch_bounds__(256) void transpose_kernel(
    const bf16s* __restrict__ src, bf16s* __restrict__ dst,
    const float* __restrict__ p_decay) {
    int b = blockIdx.z;
    long t0 = (long)blockIdx.y * 64, e0 = (long)blockIdx.x * 64;
    __shared__ bf16s tile[64][72];
    int tid = threadIdx.x;
    int r = tid >> 2, cs = (tid & 3) * 16;
    long tsrc = t0 + r - SHIFT;
    if (tsrc >= 0) {
        const bf16s* s = src + ((long)b * 4096 + tsrc) * 768 + e0 + cs;
        short8 v0 = *(const short8*)s;
        short8 v1 = *(const short8*)(s + 8);
        if (GW) {
            float gm = 1.0f / (1.0f + __expf(-p_decay[0]));
            float gwf = exp2f(__log2f(gm) * (float)(1023 - (int)(tsrc & 1023)));
#pragma unroll
            for (int i = 0; i < 8; ++i) {
                tile[r][cs + i]     = f2bf(bf2f(v0[i]) * gwf);
                tile[r][cs + 8 + i] = f2bf(bf2f(v1[i]) * gwf);
            }
        } else {
#pragma unroll
            for (int i = 0; i < 8; ++i) {
                tile[r][cs + i]     = v0[i];
                tile[r][cs + 8 + i] = v1[i];
            }
        }
    } else {
#pragma unroll
        for (int i = 0; i < 16; ++i) tile[r][cs + i] = 0;
    }
    __syncthreads();
    int er = tid >> 2, ts = (tid & 3) * 16;
    short8 a, bb;
#pragma unroll
    for (int i = 0; i < 8; ++i) a[i] = tile[ts + i][er];
#pragma unroll
    for (int i = 0; i < 8; ++i) bb[i] = tile[ts + 8 + i][er];
    bf16s* d = dst + ((long)b * 768 + e0 + er) * 4096 + t0 + ts;
    *(short8*)d = a;
    *(short8*)(d + 8) = bb;
}

// ---------------------------------------------------------------------------
// K6: W-state kernel. C=1024, Nc=4. Block owns one 128x128 tile of W[vd][kd]
// for one b. Sequentially over 4 chunks: store Wst[b][j] = acc (bf16), then
// acc = gamma^1024 * acc + U_j accumulated by MFMA over the chunk (K=1024).
// ---------------------------------------------------------------------------
__global__ __launch_bounds__(256, 2) void wstate_kernel(
    const bf16s* __restrict__ vTs, const bf16s* __restrict__ oTs,
    bf16s* __restrict__ Wst, const float* __restrict__ p_decay) {
    __shared__ bf16s sA[128 * 64];
    __shared__ bf16s sB[128 * 64];
    const int b = blockIdx.y;
    const int ti = blockIdx.x % 6, tj = blockIdx.x / 6;
    const int tid = threadIdx.x;
    const int wave = tid >> 6, lane = tid & 63;
    const int wm = wave >> 1, wn = wave & 1;
    const int ln15 = lane & 15, q = lane >> 4;
    const int sr = tid >> 3;
    const int sf = (tid & 7) ^ (sr & 7);
    const bf16s* gA = vTs + ((long)b * 768 + ti * 128 + sr) * 4096 + sf * 8;
    const bf16s* gB = oTs + ((long)b * 768 + tj * 128 + sr) * 4096 + sf * 8;
    const float gm = 1.0f / (1.0f + __expf(-p_decay[0]));
    const float gC = exp2f(__log2f(gm) * 1024.0f);
    f32x4 acc[4][4] = {};
    for (int jc = 0; jc < 4; ++jc) {
        bf16s* Wj = Wst + ((long)(b * 4 + jc)) * 768 * 768;
#pragma unroll
        for (int i = 0; i < 4; ++i)
#pragma unroll
            for (int jj = 0; jj < 4; ++jj) {
                long mb = ti * 128 + wm * 64 + i * 16 + q * 4;
                long nc = tj * 128 + wn * 64 + jj * 16 + ln15;
#pragma unroll
                for (int e = 0; e < 4; ++e) {
                    Wj[(mb + e) * 768 + nc] = f2bf(acc[i][jj][e]);
                    acc[i][jj][e] *= gC;
                }
            }
        for (int kt = 0; kt < 16; ++kt) {
            __syncthreads();
            stage128(sA, gA, 4096, wave);
            stage128(sB, gB, 4096, wave);
            gA += 64; gB += 64;
            asm volatile("s_waitcnt vmcnt(0)" ::: "memory");
            __syncthreads();
#pragma unroll
            for (int kk = 0; kk < 2; ++kk) {
                short8 af[4], bf_[4];
#pragma unroll
                for (int i = 0; i < 4; ++i) af[i] = fragr(sA, wm * 64 + i * 16 + ln15, kk, q);
#pragma unroll
                for (int j = 0; j < 4; ++j) bf_[j] = fragr(sB, wn * 64 + j * 16 + ln15, kk, q);
#pragma unroll
                for (int i = 0; i < 4; ++i)
#pragma unroll
                    for (int j = 0; j < 4; ++j) acc[i][j] = MFMA(af[i], bf_[j], acc[i][j]);
            }
        }
    }
}

// ---------------------------------------------------------------------------
// K7: P'[b,j][c][c'] = bf16( (r_c . k_c') * gamma^(c-1024) * (c>c') ).
// Lower-triangular 128x128 tiles only (cj <= ci); others never read.
// ---------------------------------------------------------------------------
__global__ __launch_bounds__(256, 2) void pmat_kernel(
    const bf16s* __restrict__ outb, bf16s* __restrict__ P,
    const float* __restrict__ p_decay) {
    const int ci = blockIdx.x >> 3, cj = blockIdx.x & 7;
    if (cj > ci) return;
    const int j = blockIdx.y, b = blockIdx.z;
    const bool fix = (j == 0 && cj == 0);
    __shared__ bf16s sA[128 * 64];
    __shared__ bf16s sB[128 * 64];
    const int tid = threadIdx.x;
    const int wave = tid >> 6, lane = tid & 63;
    const int wm = wave >> 1, wn = wave & 1;
    const int ln15 = lane & 15, q = lane >> 4;
    const int sr = tid >> 3;
    const int sf = (tid & 7) ^ (sr & 7);
    const bf16s* gA = outb + ((long)b * 4096 + j * 1024 + ci * 128 + sr) * 768 + sf * 8;
    const bf16s* gB = outb + ((long)b * 4096 + j * 1024 + cj * 128 + sr - 1) * 768 + sf * 8;
    f32x4 acc[4][4] = {};
    for (int kt = 0; kt < 12; ++kt) {
        __syncthreads();
        stage128(sA, gA, 768, wave);
        stage128(sB, gB, 768, wave);
        gA += 64; gB += 64;
        asm volatile("s_waitcnt vmcnt(0)" ::: "memory");
        __syncthreads();
        if (fix) {                         // B row 0 is global t=-1 -> zero
            if (tid < 8) { short8 zz = {0,0,0,0,0,0,0,0}; ((short8*)sB)[tid] = zz; }
            __syncthreads();
        }
#pragma unroll
        for (int kk = 0; kk < 2; ++kk) {
            short8 af[4], bf_[4];
#pragma unroll
            for (int i = 0; i < 4; ++i) af[i] = fragr(sA, wm * 64 + i * 16 + ln15, kk, q);
#pragma unroll
            for (int jj = 0; jj < 4; ++jj) bf_[jj] = fragr(sB, wn * 64 + jj * 16 + ln15, kk, q);
#pragma unroll
            for (int i = 0; i < 4; ++i)
#pragma unroll
                for (int jj = 0; jj < 4; ++jj) acc[i][jj] = MFMA(af[i], bf_[jj], acc[i][jj]);
        }
    }
    const float lg = __log2f(1.0f / (1.0f + __expf(-p_decay[0])));
    bf16s* Pb = P + ((long)(b * 4 + j) << 20);
#pragma unroll
    for (int i = 0; i < 4; ++i)
#pragma unroll
        for (int jj = 0; jj < 4; ++jj) {
            int cb_ = ci * 128 + wm * 64 + i * 16 + q * 4;
            int cp  = cj * 128 + wn * 64 + jj * 16 + ln15;
#pragma unroll
            for (int e = 0; e < 4; ++e) {
                int c = cb_ + e;
                float val = (c > cp) ? acc[i][jj][e] * exp2f(lg * (float)(c - 1024)) : 0.0f;
                Pb[(long)c * 1024 + cp] = f2bf(val);
            }
        }
}

// ---------------------------------------------------------------------------
// K8: reads[c, vd] = gamma^(c%1024) * (r_c @ Wst[b,j]^T)   [skip for j==0]
//                  + P'[b,j] @ vTs^T                        (K limited to c'<=c)
// ---------------------------------------------------------------------------
__global__ __launch_bounds__(256, 2) void reads_kernel(
    const bf16s* __restrict__ outb, const bf16s* __restrict__ Wst,
    const bf16s* __restrict__ Pm, const bf16s* __restrict__ vTs,
    bf16s* __restrict__ readsb, const float* __restrict__ p_decay) {
    const int ci = blockIdx.x & 7, vi = blockIdx.x >> 3;
    const int j = blockIdx.y, b = blockIdx.z;
    __shared__ bf16s sA[128 * 64];
    __shared__ bf16s sB[128 * 64];
    const int tid = threadIdx.x;
    const int wave = tid >> 6, lane = tid & 63;
    const int wm = wave >> 1, wn = wave & 1;
    const int ln15 = lane & 15, q = lane >> 4;
    const int sr = tid >> 3;
    const int sf = (tid & 7) ^ (sr & 7);
    const float lg = __log2f(1.0f / (1.0f + __expf(-p_decay[0])));
    f32x4 acc[4][4] = {};
    if (j > 0) {
        const bf16s* gA = outb + ((long)b * 4096 + j * 1024 + ci * 128 + sr) * 768 + sf * 8;
        const bf16s* gB = Wst + ((long)(b * 4 + j) * 768 + vi * 128 + sr) * 768 + sf * 8;
        for (int kt = 0; kt < 12; ++kt) {
            __syncthreads();
            stage128(sA, gA, 768, wave);
            stage128(sB, gB, 768, wave);
            gA += 64; gB += 64;
            asm volatile("s_waitcnt vmcnt(0)" ::: "memory");
            __syncthreads();
#pragma unroll
            for (int kk = 0; kk < 2; ++kk) {
                short8 af[4], bf_[4];
#pragma unroll
                for (int i = 0; i < 4; ++i) af[i] = fragr(sA, wm * 64 + i * 16 + ln15, kk, q);
#pragma unroll
                for (int jj = 0; jj < 4; ++jj) bf_[jj] = fragr(sB, wn * 64 + jj * 16 + ln15, kk, q);
#pragma unroll
                for (int i = 0; i < 4; ++i)
#pragma unroll
                    for (int jj = 0; jj < 4; ++jj) acc[i][jj] = MFMA(af[i], bf_[jj], acc[i][jj]);
            }
        }
#pragma unroll
        for (int i = 0; i < 4; ++i) {
            int cb_ = ci * 128 + wm * 64 + i * 16 + q * 4;
#pragma unroll
            for (int e = 0; e < 4; ++e) {
                float s = exp2f(lg * (float)(cb_ + e));
#pragma unroll
                for (int jj = 0; jj < 4; ++jj) acc[i][jj][e] *= s;
            }
        }
    }
    {
        const bf16s* gA = Pm + ((long)(b * 4 + j) << 20) + (long)(ci * 128 + sr) * 1024 + sf * 8;
        const bf16s* gB = vTs + ((long)b * 768 + vi * 128 + sr) * 4096 + j * 1024 + sf * 8;
        const int nkt = 2 * (ci + 1);
        for (int kt = 0; kt < nkt; ++kt) {
            __syncthreads();
            stage128(sA, gA, 1024, wave);
            stage128(sB, gB, 4096, wave);
            gA += 64; gB += 64;
            asm volatile("s_waitcnt vmcnt(0)" ::: "memory");
            __syncthreads();
#pragma unroll
            for (int kk = 0; kk < 2; ++kk) {
                short8 af[4], bf_[4];
#pragma unroll
                for (int i = 0; i < 4; ++i) af[i] = fragr(sA, wm * 64 + i * 16 + ln15, kk, q);
#pragma unroll
                for (int jj = 0; jj < 4; ++jj) bf_[jj] = fragr(sB, wn * 64 + jj * 16 + ln15, kk, q);
#pragma unroll
                for (int i = 0; i < 4; ++i)
#pragma unroll
                    for (int jj = 0; jj < 4; ++jj) acc[i][jj] = MFMA(af[i], bf_[jj], acc[i][jj]);
            }
        }
    }
#pragma unroll
    for (int i = 0; i < 4; ++i)
#pragma unroll
        for (int jj = 0; jj < 4; ++jj) {
            long tb = (long)j * 1024 + ci * 128 + wm * 64 + i * 16 + q * 4;
            long nc = vi * 128 + wn * 64 + jj * 16 + ln15;
#pragma unroll
            for (int e = 0; e < 4; ++e)
                readsb[((long)b * 4096 + tb + e) * 768 + nc] = f2bf(acc[i][jj][e]);
        }
}

// ---------------------------------------------------------------------------
extern "C" void kernel_launch(void* const* d_in, const int* in_sizes, int n_in,
                              void* d_out, int out_size, void* d_ws, size_t ws_size,
                              hipStream_t stream) {
    (void)in_sizes; (void)n_in; (void)out_size;
    const float* x      = (const float*)d_in[0];
    const float* norm_w = (const float*)d_in[1];
    const float* proj_w = (const float*)d_in[2];
    const float* gate_w = (const float*)d_in[3];
    const float* conv_w = (const float*)d_in[4];
    const float* conv_b = (const float*)d_in[5];
    const float* op_w   = (const float*)d_in[6];
    const float* wr_w   = (const float*)d_in[7];
    const float* rd_w   = (const float*)d_in[8];
    const float* decay  = (const float*)d_in[9];
    const float* la     = (const float*)d_in[10];

    // -------- workspace layout (liveness overlays), ~312.4 MB total --------
    char* ws = (char*)d_ws;
    size_t off = 0;
    auto alloc = [&](size_t bytes) { void* p = ws + off; off += (bytes + 255) & ~(size_t)255; return p; };
    bf16s* w_pg = (bf16s*)alloc(3072l * 768 * 2);          // 4.7 MB
    bf16s* w_op = (bf16s*)alloc(768l * 1536 * 2);          // 2.4 MB
    bf16s* w_wr = (bf16s*)alloc(768l * 768 * 2);           // 1.2 MB
    bf16s* w_rd = (bf16s*)alloc(768l * 768 * 2);           // 1.2 MB
    bf16s* RA   = (bf16s*)alloc(32768l * 768 * 2);         // 50.3 MB: xn | vTs
    bf16s* RB   = (bf16s*)alloc(2 * 32768l * 768 * 2);     // 100.7 MB: pg | vb+oTs | P'
    bf16s* RC   = (bf16s*)alloc(2 * 32768l * 768 * 2);     // 100.7 MB: vg | Wst+reads
    bf16s* RE   = (bf16s*)alloc(32768l * 768 * 2);         // 50.3 MB: outb
    if (ws_size < off) return;   // diagnostic guard: fail clean, don't fault

    bf16s* xn    = RA;
    bf16s* vTs   = RA;
    bf16s* pgH   = RB;                     // 16384 x 3072 (one M-half)
    bf16s* vb    = RB;                     // [0:50.3 MB]
    bf16s* oTs   = RB + 25165824;          // [50.3:100.7 MB]
    bf16s* Pm    = RB;                     // 67.1 MB (after vb & oTs are dead)
    bf16s* vg    = RC;                     // 32768 x 1536
    bf16s* Wst   = RC;                     // 37.75 MB (after vg dead)
    bf16s* readsb= RC + 18874368;          // [37.75:88.1 MB]
    bf16s* outb  = RE;

    hipLaunchKernelGGL(cast_w_kernel, dim3(18432), dim3(256), 0, stream,
                       proj_w, gate_w, op_w, wr_w, rd_w, w_pg, w_op, w_wr, w_rd);
    hipLaunchKernelGGL(rmsnorm_kernel, dim3(32768), dim3(256), 0, stream, x, norm_w, xn);
    // proj+gate GEMM + conv, split at the batch-4 boundary (no conv halo)
    for (int h = 0; h < 2; ++h) {
        hipLaunchKernelGGL(HIP_KERNEL_NAME(gemm8_kernel<0>), dim3(12, 64), dim3(512), 0, stream,
                           xn + (long)h * 16384 * 768, w_pg, 768, 3072, pgH,
                           (const float*)nullptr, (const bf16s*)nullptr, la, (float*)nullptr);
        hipLaunchKernelGGL(conv_kernel, dim3(1024), dim3(192), 0, stream,
                           pgH, conv_w, conv_b, vg + (long)h * 16384 * 1536);
    }
    hipLaunchKernelGGL(HIP_KERNEL_NAME(gemm8_kernel<0>), dim3(3, 128), dim3(512), 0, stream,
                       vg, w_op, 1536, 768, outb,
                       (const float*)nullptr, (const bf16s*)nullptr, la, (float*)nullptr);
    hipLaunchKernelGGL(HIP_KERNEL_NAME(gemm8_kernel<0>), dim3(3, 128), dim3(512), 0, stream,
                       outb, w_wr, 768, 768, vb,
                       (const float*)nullptr, (const bf16s*)nullptr, la, (float*)nullptr);
    hipLaunchKernelGGL(HIP_KERNEL_NAME(transpose_kernel<1, 0>), dim3(12, 64, 8), dim3(256), 0, stream,
                       outb, oTs, decay);
    hipLaunchKernelGGL(HIP_KERNEL_NAME(transpose_kernel<0, 1>), dim3(12, 64, 8), dim3(256), 0, stream,
                       vb, vTs, decay);
    hipLaunchKernelGGL(wstate_kernel, dim3(36, 8), dim3(256), 0, stream,
                       vTs, oTs, Wst, decay);
    hipLaunchKernelGGL(pmat_kernel, dim3(64, 4, 8), dim3(256), 0, stream,
                       outb, Pm, decay);          // clobbers vb+oTs (both dead)
    hipLaunchKernelGGL(reads_kernel, dim3(48, 4, 8), dim3(256), 0, stream,
                       outb, Wst, Pm, vTs, readsb, decay);
    hipLaunchKernelGGL(HIP_KERNEL_NAME(gemm8_kernel<1>), dim3(3, 128), dim3(512), 0, stream,
                       readsb, w_rd, 768, 768, (bf16s*)nullptr,
                       x, outb, la, (float*)d_out);
}

// Round 2
// 939.240 us; speedup vs baseline: 1.1152x; 1.1152x over previous
//
#include <hip/hip_runtime.h>
#include <stdint.h>

// ----------------------------------------------------------------------------
// HebbianLayer on MI355X (gfx950).
// B=8, T=4096, D=768, d_inner=1536, reference CHUNK=64.
// R3: scan re-chunked to C=1024 -> 3 parallel GEMM kernels (wstate/pmat/reads).
// R4: conv rewritten as sliding-window streaming kernel.
// R5: 256x256 8-phase GEMM engine — REGRESSED (-65 us): N=768 shapes give
// 384-block grids at 1 block/CU -> tail + lost inter-block TLP. Reverted.
// R6: back to 128^2 2-barrier engine; + XCD-chunked block swizzle in gemm
// (same-A tiles -> same XCD L2); + reads_kernel heavy-first launch order
// (j=0 / low-ci blocks were launching first, heaviest last -> drain tail,
// 24% achieved occupancy).
// ----------------------------------------------------------------------------

typedef short bf16s;                                            // raw bf16 bits
typedef __attribute__((ext_vector_type(8))) short short8;       // 4 VGPR mfma frag
typedef __attribute__((ext_vector_type(4))) float f32x4;        // mfma acc

#define DEVINL __device__ __forceinline__

DEVINL float bf2f(short s) {
    union { unsigned u; float f; } v; v.u = ((unsigned)(unsigned short)s) << 16; return v.f;
}
DEVINL short f2bf(float f) {
    union { float f; unsigned u; } v; v.f = f;
    unsigned r = v.u + 0x7fffu + ((v.u >> 16) & 1u);            // RNE
    return (short)(r >> 16);
}

// async global->LDS, 16B per lane. LDS dest must be wave-uniform.
DEVINL void glds16(void* lds, const void* g) {
    __builtin_amdgcn_global_load_lds(
        (const __attribute__((address_space(1))) void*)g,
        (__attribute__((address_space(3))) void*)lds, 16, 0, 0);
}

// Stage a 128-row x 64-col bf16 tile. g must be pre-offset by
// sr*gstride + sf*8 where sr=tid>>3, sf=(tid&7)^(sr&7) (XOR slot swizzle).
DEVINL void stage128(bf16s* lds, const bf16s* g, long gstride, int wave) {
#pragma unroll
    for (int p = 0; p < 4; ++p)
        glds16(lds + p * 2048 + wave * 512, g + (long)p * 32 * gstride);
}

// Read an A/B fragment from a swizzled 64-col tile.
DEVINL short8 fragr(const bf16s* t, int row, int kk, int q) {
    int f = kk * 4 + q;
    return *(const short8*)(t + row * 64 + ((f ^ (row & 7)) * 8));
}

#define MFMA(a, b, c) __builtin_amdgcn_mfma_f32_16x16x32_bf16((a), (b), (c), 0, 0, 0)

// ---------------------------------------------------------------------------
// K0: weight casts (fp32 -> bf16). w_pg = [proj_w ; gate_w] rows (3072x768).
// ---------------------------------------------------------------------------
__global__ __launch_bounds__(256) void cast_w_kernel(
    const float* __restrict__ proj, const float* __restrict__ gate,
    const float* __restrict__ op, const float* __restrict__ wr, const float* __restrict__ rd,
    bf16s* __restrict__ w_pg, bf16s* __restrict__ w_op, bf16s* __restrict__ w_wr,
    bf16s* __restrict__ w_rd) {
    long i = (long)blockIdx.x * 256 + threadIdx.x;
    if (i < 1179648)        w_pg[i] = f2bf(proj[i]);
    else if (i < 2359296)   w_pg[i] = f2bf(gate[i - 1179648]);
    else if (i < 3538944)   w_op[i - 2359296] = f2bf(op[i - 2359296]);
    else if (i < 4128768)   w_wr[i - 3538944] = f2bf(wr[i - 3538944]);
    else if (i < 4718592)   w_rd[i - 4128768] = f2bf(rd[i - 4128768]);
}

// ---------------------------------------------------------------------------
// K1: RMSNorm + cast. One block per row (768 elems).
// ---------------------------------------------------------------------------
__global__ __launch_bounds__(256) void rmsnorm_kernel(
    const float* __restrict__ x, const float* __restrict__ w, bf16s* __restrict__ xn) {
    long row = blockIdx.x;
    const float* xr = x + row * 768;
    int tid = threadIdx.x;
    float v0 = xr[tid], v1 = xr[tid + 256], v2 = xr[tid + 512];
    float ss = v0 * v0 + v1 * v1 + v2 * v2;
#pragma unroll
    for (int off = 32; off; off >>= 1) ss += __shfl_down(ss, off);
    __shared__ float p[4];
    if ((tid & 63) == 0) p[tid >> 6] = ss;
    __syncthreads();
    float tot = p[0] + p[1] + p[2] + p[3];
    float s = rsqrtf(tot * (1.0f / 768.0f) + 1e-5f);
    bf16s* o = xn + row * 768;
    o[tid]       = f2bf(v0 * s * w[tid]);
    o[tid + 256] = f2bf(v1 * s * w[tid + 256]);
    o[tid + 512] = f2bf(v2 * s * w[tid + 512]);
}

// ---------------------------------------------------------------------------
// GEMM: C[M,N] = A[M,K] @ B[N,K]^T. 128x128 tile, BK=64, 4 waves 2x2.
// MODE 0: store bf16.   MODE 1: d_out = x + bf2f(outres) + exp(la)*acc (f32).
// R6: XCD-chunked block swizzle — each XCD gets a contiguous logical range
// (consecutive by, all bx) so A-panels stay resident in that XCD's L2.
// All grids used have (gx*gy) % 8 == 0 (3072 / 1536), so the simple
// bijective form applies.
// ---------------------------------------------------------------------------
template <int MODE>
__global__ __launch_bounds__(256, 2) void gemm_kernel(
    const bf16s* __restrict__ A, const bf16s* __restrict__ B, int K, int N,
    bf16s* __restrict__ Cb, const float* __restrict__ xres,
    const bf16s* __restrict__ outres, const float* __restrict__ p_la,
    float* __restrict__ Cout) {
    __shared__ bf16s sA[128 * 64];
    __shared__ bf16s sB[128 * 64];
    const int tid = threadIdx.x;
    const int wave = tid >> 6, lane = tid & 63;
    const int wm = wave >> 1, wn = wave & 1;
    const int ln15 = lane & 15, q = lane >> 4;
    // XCD-chunked swizzle (bijective; nb % 8 == 0 for all launches)
    const int nbx = gridDim.x;
    const int nb = nbx * gridDim.y;
    const int l = blockIdx.y * nbx + blockIdx.x;
    const int L = (l & 7) * (nb >> 3) + (l >> 3);
    const int bx = L % nbx, by = L / nbx;
    const long m0 = (long)by * 128, n0 = (long)bx * 128;
    const int sr = tid >> 3;
    const int sf = (tid & 7) ^ (sr & 7);
    const bf16s* gA = A + (m0 + sr) * K + sf * 8;
    const bf16s* gB = B + (n0 + sr) * K + sf * 8;
    f32x4 acc[4][4] = {};
    const int nkt = K >> 6;
    for (int kt = 0; kt < nkt; ++kt) {
        __syncthreads();
        stage128(sA, gA, K, wave);
        stage128(sB, gB, K, wave);
        gA += 64; gB += 64;
        asm volatile("s_waitcnt vmcnt(0)" ::: "memory");
        __syncthreads();
#pragma unroll
        for (int kk = 0; kk < 2; ++kk) {
            short8 af[4], bf_[4];
#pragma unroll
            for (int i = 0; i < 4; ++i) af[i] = fragr(sA, wm * 64 + i * 16 + ln15, kk, q);
#pragma unroll
            for (int j = 0; j < 4; ++j) bf_[j] = fragr(sB, wn * 64 + j * 16 + ln15, kk, q);
#pragma unroll
            for (int i = 0; i < 4; ++i)
#pragma unroll
                for (int j = 0; j < 4; ++j) acc[i][j] = MFMA(af[i], bf_[j], acc[i][j]);
        }
    }
    float alpha = 0.f;
    if (MODE == 1) alpha = __expf(p_la[0]);
#pragma unroll
    for (int i = 0; i < 4; ++i)
#pragma unroll
        for (int j = 0; j < 4; ++j) {
            long mb = m0 + wm * 64 + i * 16 + q * 4;
            long nc = n0 + wn * 64 + j * 16 + ln15;
#pragma unroll
            for (int e = 0; e < 4; ++e) {
                long m = mb + e;
                float v = acc[i][j][e];
                if (MODE == 0) {
                    Cb[m * N + nc] = f2bf(v);
                } else {
                    long idx = m * 768 + nc;
                    Cout[idx] = xres[idx] + bf2f(outres[idx]) + alpha * v;
                }
            }
        }
}

// ---------------------------------------------------------------------------
// K3: depthwise causal conv(4) + bias + SiLU, gated by SiLU(gate).
// Sliding-window streaming version: thread owns 8 channels x 16 time steps.
// ---------------------------------------------------------------------------
__global__ __launch_bounds__(192) void conv_kernel(
    const bf16s* __restrict__ pg, const float* __restrict__ cw,
    const float* __restrict__ cb, bf16s* __restrict__ vg) {
    const int e0 = threadIdx.x * 8;
    const long l0 = (long)blockIdx.x * 16;
    float w0[8], w1[8], w2[8], w3[8], bias[8];
#pragma unroll
    for (int i = 0; i < 8; ++i) {
        const float* wc = cw + (e0 + i) * 4;
        w0[i] = wc[0]; w1[i] = wc[1]; w2[i] = wc[2]; w3[i] = wc[3];
        bias[i] = cb[e0 + i];
    }
    const bf16s* base = pg + l0 * 3072 + e0;
    short8 h0, h1, h2;
    if ((l0 & 4095) == 0) {
        short8 z = {0, 0, 0, 0, 0, 0, 0, 0};
        h0 = z; h1 = z; h2 = z;
    } else {
        h0 = *(const short8*)(base - 3 * 3072);
        h1 = *(const short8*)(base - 2 * 3072);
        h2 = *(const short8*)(base - 1 * 3072);
    }
    short8 cur = *(const short8*)base;
    short8 g8  = *(const short8*)(base + 1536);
    bf16s* out = vg + l0 * 1536 + e0;
#pragma unroll 4
    for (int t = 0; t < 16; ++t) {
        short8 ncur, ng;
        if (t < 15) {                       // prefetch next row
            ncur = *(const short8*)(base + 3072);
            ng   = *(const short8*)(base + 3072 + 1536);
        }
        short8 o;
#pragma unroll
        for (int i = 0; i < 8; ++i) {
            float vv = bias[i] + bf2f(h0[i]) * w0[i] + bf2f(h1[i]) * w1[i]
                     + bf2f(h2[i]) * w2[i] + bf2f(cur[i]) * w3[i];
            float sv = vv / (1.0f + __expf(-vv));
            float gg = bf2f(g8[i]);
            o[i] = f2bf(sv * (gg / (1.0f + __expf(-gg))));
        }
        *(short8*)out = o;
        h0 = h1; h1 = h2; h2 = cur;
        cur = ncur; g8 = ng;
        base += 3072; out += 1536;
    }
}

// ---------------------------------------------------------------------------
// K5: transpose [b][t][e] -> [b][e][t], optional shift (t -> t-1, zero fill)
// and optional gw scale gamma^(1023 - t%1024). bf16 -> bf16.
// ---------------------------------------------------------------------------
template <int SHIFT, int GW>
__global__ __launch_bounds__(256) void transpose_kernel(
    const bf16s* __restrict__ src, bf16s* __restrict__ dst,
    const float* __restrict__ p_decay) {
    int b = blockIdx.z;
    long t0 = (long)blockIdx.y * 64, e0 = (long)blockIdx.x * 64;
    __shared__ bf16s tile[64][72];
    int tid = threadIdx.x;
    int r = tid >> 2, cs = (tid & 3) * 16;
    long tsrc = t0 + r - SHIFT;
    if (tsrc >= 0) {
        const bf16s* s = src + ((long)b * 4096 + tsrc) * 768 + e0 + cs;
        short8 v0 = *(const short8*)s;
        short8 v1 = *(const short8*)(s + 8);
        if (GW) {
            float gm = 1.0f / (1.0f + __expf(-p_decay[0]));
            float gwf = exp2f(__log2f(gm) * (float)(1023 - (int)(tsrc & 1023)));
#pragma unroll
            for (int i = 0; i < 8; ++i) {
                tile[r][cs + i]     = f2bf(bf2f(v0[i]) * gwf);
                tile[r][cs + 8 + i] = f2bf(bf2f(v1[i]) * gwf);
            }
        } else {
#pragma unroll
            for (int i = 0; i < 8; ++i) {
                tile[r][cs + i]     = v0[i];
                tile[r][cs + 8 + i] = v1[i];
            }
        }
    } else {
#pragma unroll
        for (int i = 0; i < 16; ++i) tile[r][cs + i] = 0;
    }
    __syncthreads();
    int er = tid >> 2, ts = (tid & 3) * 16;
    short8 a, bb;
#pragma unroll
    for (int i = 0; i < 8; ++i) a[i] = tile[ts + i][er];
#pragma unroll
    for (int i = 0; i < 8; ++i) bb[i] = tile[ts + 8 + i][er];
    bf16s* d = dst + ((long)b * 768 + e0 + er) * 4096 + t0 + ts;
    *(short8*)d = a;
    *(short8*)(d + 8) = bb;
}

// ---------------------------------------------------------------------------
// K6: W-state kernel. C=1024, Nc=4. Block owns one 128x128 tile of W[vd][kd]
// for one b. Sequentially over 4 chunks: store Wst[b][j] = acc (bf16), then
// acc = gamma^1024 * acc + U_j accumulated by MFMA over the chunk (K=1024).
// ---------------------------------------------------------------------------
__global__ __launch_bounds__(256, 2) void wstate_kernel(
    const bf16s* __restrict__ vTs, const bf16s* __restrict__ oTs,
    bf16s* __restrict__ Wst, const float* __restrict__ p_decay) {
    __shared__ bf16s sA[128 * 64];
    __shared__ bf16s sB[128 * 64];
    const int b = blockIdx.y;
    const int ti = blockIdx.x % 6, tj = blockIdx.x / 6;
    const int tid = threadIdx.x;
    const int wave = tid >> 6, lane = tid & 63;
    const int wm = wave >> 1, wn = wave & 1;
    const int ln15 = lane & 15, q = lane >> 4;
    const int sr = tid >> 3;
    const int sf = (tid & 7) ^ (sr & 7);
    const bf16s* gA = vTs + ((long)b * 768 + ti * 128 + sr) * 4096 + sf * 8;
    const bf16s* gB = oTs + ((long)b * 768 + tj * 128 + sr) * 4096 + sf * 8;
    const float gm = 1.0f / (1.0f + __expf(-p_decay[0]));
    const float gC = exp2f(__log2f(gm) * 1024.0f);
    f32x4 acc[4][4] = {};
    for (int jc = 0; jc < 4; ++jc) {
        bf16s* Wj = Wst + ((long)(b * 4 + jc)) * 768 * 768;
#pragma unroll
        for (int i = 0; i < 4; ++i)
#pragma unroll
            for (int jj = 0; jj < 4; ++jj) {
                long mb = ti * 128 + wm * 64 + i * 16 + q * 4;
                long nc = tj * 128 + wn * 64 + jj * 16 + ln15;
#pragma unroll
                for (int e = 0; e < 4; ++e) {
                    Wj[(mb + e) * 768 + nc] = f2bf(acc[i][jj][e]);
                    acc[i][jj][e] *= gC;
                }
            }
        for (int kt = 0; kt < 16; ++kt) {
            __syncthreads();
            stage128(sA, gA, 4096, wave);
            stage128(sB, gB, 4096, wave);
            gA += 64; gB += 64;
            asm volatile("s_waitcnt vmcnt(0)" ::: "memory");
            __syncthreads();
#pragma unroll
            for (int kk = 0; kk < 2; ++kk) {
                short8 af[4], bf_[4];
#pragma unroll
                for (int i = 0; i < 4; ++i) af[i] = fragr(sA, wm * 64 + i * 16 + ln15, kk, q);
#pragma unroll
                for (int j = 0; j < 4; ++j) bf_[j] = fragr(sB, wn * 64 + j * 16 + ln15, kk, q);
#pragma unroll
                for (int i = 0; i < 4; ++i)
#pragma unroll
                    for (int j = 0; j < 4; ++j) acc[i][j] = MFMA(af[i], bf_[j], acc[i][j]);
            }
        }
    }
}

// ---------------------------------------------------------------------------
// K7: P'[b,j][c][c'] = bf16( (r_c . k_c') * gamma^(c-1024) * (c>c') ).
// Lower-triangular 128x128 tiles only (cj <= ci); others never read.
// ---------------------------------------------------------------------------
__global__ __launch_bounds__(256, 2) void pmat_kernel(
    const bf16s* __restrict__ outb, bf16s* __restrict__ P,
    const float* __restrict__ p_decay) {
    const int ci = blockIdx.x >> 3, cj = blockIdx.x & 7;
    if (cj > ci) return;
    const int j = blockIdx.y, b = blockIdx.z;
    const bool fix = (j == 0 && cj == 0);
    __shared__ bf16s sA[128 * 64];
    __shared__ bf16s sB[128 * 64];
    const int tid = threadIdx.x;
    const int wave = tid >> 6, lane = tid & 63;
    const int wm = wave >> 1, wn = wave & 1;
    const int ln15 = lane & 15, q = lane >> 4;
    const int sr = tid >> 3;
    const int sf = (tid & 7) ^ (sr & 7);
    const bf16s* gA = outb + ((long)b * 4096 + j * 1024 + ci * 128 + sr) * 768 + sf * 8;
    const bf16s* gB = outb + ((long)b * 4096 + j * 1024 + cj * 128 + sr - 1) * 768 + sf * 8;
    f32x4 acc[4][4] = {};
    for (int kt = 0; kt < 12; ++kt) {
        __syncthreads();
        stage128(sA, gA, 768, wave);
        stage128(sB, gB, 768, wave);
        gA += 64; gB += 64;
        asm volatile("s_waitcnt vmcnt(0)" ::: "memory");
        __syncthreads();
        if (fix) {                         // B row 0 is global t=-1 -> zero
            if (tid < 8) { short8 zz = {0,0,0,0,0,0,0,0}; ((short8*)sB)[tid] = zz; }
            __syncthreads();
        }
#pragma unroll
        for (int kk = 0; kk < 2; ++kk) {
            short8 af[4], bf_[4];
#pragma unroll
            for (int i = 0; i < 4; ++i) af[i] = fragr(sA, wm * 64 + i * 16 + ln15, kk, q);
#pragma unroll
            for (int jj = 0; jj < 4; ++jj) bf_[jj] = fragr(sB, wn * 64 + jj * 16 + ln15, kk, q);
#pragma unroll
            for (int i = 0; i < 4; ++i)
#pragma unroll
                for (int jj = 0; jj < 4; ++jj) acc[i][jj] = MFMA(af[i], bf_[jj], acc[i][jj]);
        }
    }
    const float lg = __log2f(1.0f / (1.0f + __expf(-p_decay[0])));
    bf16s* Pb = P + ((long)(b * 4 + j) << 20);
#pragma unroll
    for (int i = 0; i < 4; ++i)
#pragma unroll
        for (int jj = 0; jj < 4; ++jj) {
            int cb_ = ci * 128 + wm * 64 + i * 16 + q * 4;
            int cp  = cj * 128 + wn * 64 + jj * 16 + ln15;
#pragma unroll
            for (int e = 0; e < 4; ++e) {
                int c = cb_ + e;
                float val = (c > cp) ? acc[i][jj][e] * exp2f(lg * (float)(c - 1024)) : 0.0f;
                Pb[(long)c * 1024 + cp] = f2bf(val);
            }
        }
}

// ---------------------------------------------------------------------------
// K8: reads[c, vd] = gamma^(c%1024) * (r_c @ Wst[b,j]^T)   [skip for j==0]
//                  + P'[b,j] @ vTs^T                        (K limited to c'<=c)
// R6: heavy-first launch order. Work per block = [j>0]*12 + 2*(ci+1) K-tiles
// (2..28). Old order launched light blocks first, heaviest last -> drain
// tail (24% achieved occupancy). Remap: j = (y+1)&3 puts j=0 (light) last;
// ci = 7-(x&7) puts high-ci (heavy) first. Same-A blocks stay 8-apart in x
// (same XCD under round-robin), so L2 A-panel reuse is preserved.
// ---------------------------------------------------------------------------
__global__ __launch_bounds__(256, 2) void reads_kernel(
    const bf16s* __restrict__ outb, const bf16s* __restrict__ Wst,
    const bf16s* __restrict__ Pm, const bf16s* __restrict__ vTs,
    bf16s* __restrict__ readsb, const float* __restrict__ p_decay) {
    const int ci = 7 - (blockIdx.x & 7), vi = blockIdx.x >> 3;
    const int j = (blockIdx.y + 1) & 3, b = blockIdx.z;
    __shared__ bf16s sA[128 * 64];
    __shared__ bf16s sB[128 * 64];
    const int tid = threadIdx.x;
    const int wave = tid >> 6, lane = tid & 63;
    const int wm = wave >> 1, wn = wave & 1;
    const int ln15 = lane & 15, q = lane >> 4;
    const int sr = tid >> 3;
    const int sf = (tid & 7) ^ (sr & 7);
    const float lg = __log2f(1.0f / (1.0f + __expf(-p_decay[0])));
    f32x4 acc[4][4] = {};
    if (j > 0) {
        const bf16s* gA = outb + ((long)b * 4096 + j * 1024 + ci * 128 + sr) * 768 + sf * 8;
        const bf16s* gB = Wst + ((long)(b * 4 + j) * 768 + vi * 128 + sr) * 768 + sf * 8;
        for (int kt = 0; kt < 12; ++kt) {
            __syncthreads();
            stage128(sA, gA, 768, wave);
            stage128(sB, gB, 768, wave);
            gA += 64; gB += 64;
            asm volatile("s_waitcnt vmcnt(0)" ::: "memory");
            __syncthreads();
#pragma unroll
            for (int kk = 0; kk < 2; ++kk) {
                short8 af[4], bf_[4];
#pragma unroll
                for (int i = 0; i < 4; ++i) af[i] = fragr(sA, wm * 64 + i * 16 + ln15, kk, q);
#pragma unroll
                for (int jj = 0; jj < 4; ++jj) bf_[jj] = fragr(sB, wn * 64 + jj * 16 + ln15, kk, q);
#pragma unroll
                for (int i = 0; i < 4; ++i)
#pragma unroll
                    for (int jj = 0; jj < 4; ++jj) acc[i][jj] = MFMA(af[i], bf_[jj], acc[i][jj]);
            }
        }
#pragma unroll
        for (int i = 0; i < 4; ++i) {
            int cb_ = ci * 128 + wm * 64 + i * 16 + q * 4;
#pragma unroll
            for (int e = 0; e < 4; ++e) {
                float s = exp2f(lg * (float)(cb_ + e));
#pragma unroll
                for (int jj = 0; jj < 4; ++jj) acc[i][jj][e] *= s;
            }
        }
    }
    {
        const bf16s* gA = Pm + ((long)(b * 4 + j) << 20) + (long)(ci * 128 + sr) * 1024 + sf * 8;
        const bf16s* gB = vTs + ((long)b * 768 + vi * 128 + sr) * 4096 + j * 1024 + sf * 8;
        const int nkt = 2 * (ci + 1);
        for (int kt = 0; kt < nkt; ++kt) {
            __syncthreads();
            stage128(sA, gA, 1024, wave);
            stage128(sB, gB, 4096, wave);
            gA += 64; gB += 64;
            asm volatile("s_waitcnt vmcnt(0)" ::: "memory");
            __syncthreads();
#pragma unroll
            for (int kk = 0; kk < 2; ++kk) {
                short8 af[4], bf_[4];
#pragma unroll
                for (int i = 0; i < 4; ++i) af[i] = fragr(sA, wm * 64 + i * 16 + ln15, kk, q);
#pragma unroll
                for (int jj = 0; jj < 4; ++jj) bf_[jj] = fragr(sB, wn * 64 + jj * 16 + ln15, kk, q);
#pragma unroll
                for (int i = 0; i < 4; ++i)
#pragma unroll
                    for (int jj = 0; jj < 4; ++jj) acc[i][jj] = MFMA(af[i], bf_[jj], acc[i][jj]);
            }
        }
    }
#pragma unroll
    for (int i = 0; i < 4; ++i)
#pragma unroll
        for (int jj = 0; jj < 4; ++jj) {
            long tb = (long)j * 1024 + ci * 128 + wm * 64 + i * 16 + q * 4;
            long nc = vi * 128 + wn * 64 + jj * 16 + ln15;
#pragma unroll
            for (int e = 0; e < 4; ++e)
                readsb[((long)b * 4096 + tb + e) * 768 + nc] = f2bf(acc[i][jj][e]);
        }
}

// ---------------------------------------------------------------------------
extern "C" void kernel_launch(void* const* d_in, const int* in_sizes, int n_in,
                              void* d_out, int out_size, void* d_ws, size_t ws_size,
                              hipStream_t stream) {
    (void)in_sizes; (void)n_in; (void)out_size;
    const float* x      = (const float*)d_in[0];
    const float* norm_w = (const float*)d_in[1];
    const float* proj_w = (const float*)d_in[2];
    const float* gate_w = (const float*)d_in[3];
    const float* conv_w = (const float*)d_in[4];
    const float* conv_b = (const float*)d_in[5];
    const float* op_w   = (const float*)d_in[6];
    const float* wr_w   = (const float*)d_in[7];
    const float* rd_w   = (const float*)d_in[8];
    const float* decay  = (const float*)d_in[9];
    const float* la     = (const float*)d_in[10];

    // -------- workspace layout (liveness overlays), ~312.4 MB total --------
    char* ws = (char*)d_ws;
    size_t off = 0;
    auto alloc = [&](size_t bytes) { void* p = ws + off; off += (bytes + 255) & ~(size_t)255; return p; };
    bf16s* w_pg = (bf16s*)alloc(3072l * 768 * 2);          // 4.7 MB
    bf16s* w_op = (bf16s*)alloc(768l * 1536 * 2);          // 2.4 MB
    bf16s* w_wr = (bf16s*)alloc(768l * 768 * 2);           // 1.2 MB
    bf16s* w_rd = (bf16s*)alloc(768l * 768 * 2);           // 1.2 MB
    bf16s* RA   = (bf16s*)alloc(32768l * 768 * 2);         // 50.3 MB: xn | vTs
    bf16s* RB   = (bf16s*)alloc(2 * 32768l * 768 * 2);     // 100.7 MB: pg | vb+oTs | P'
    bf16s* RC   = (bf16s*)alloc(2 * 32768l * 768 * 2);     // 100.7 MB: vg | Wst+reads
    bf16s* RE   = (bf16s*)alloc(32768l * 768 * 2);         // 50.3 MB: outb
    if (ws_size < off) return;   // diagnostic guard: fail clean, don't fault

    bf16s* xn    = RA;
    bf16s* vTs   = RA;
    bf16s* pgH   = RB;                     // 16384 x 3072 (one M-half)
    bf16s* vb    = RB;                     // [0:50.3 MB]
    bf16s* oTs   = RB + 25165824;          // [50.3:100.7 MB]
    bf16s* Pm    = RB;                     // 67.1 MB (after vb & oTs are dead)
    bf16s* vg    = RC;                     // 32768 x 1536
    bf16s* Wst   = RC;                     // 37.75 MB (after vg dead)
    bf16s* readsb= RC + 18874368;          // [37.75:88.1 MB]
    bf16s* outb  = RE;

    hipLaunchKernelGGL(cast_w_kernel, dim3(18432), dim3(256), 0, stream,
                       proj_w, gate_w, op_w, wr_w, rd_w, w_pg, w_op, w_wr, w_rd);
    hipLaunchKernelGGL(rmsnorm_kernel, dim3(32768), dim3(256), 0, stream, x, norm_w, xn);
    // proj+gate GEMM + conv, split at the batch-4 boundary (no conv halo)
    for (int h = 0; h < 2; ++h) {
        hipLaunchKernelGGL(HIP_KERNEL_NAME(gemm_kernel<0>), dim3(24, 128), dim3(256), 0, stream,
                           xn + (long)h * 16384 * 768, w_pg, 768, 3072, pgH,
                           (const float*)nullptr, (const bf16s*)nullptr, la, (float*)nullptr);
        hipLaunchKernelGGL(conv_kernel, dim3(1024), dim3(192), 0, stream,
                           pgH, conv_w, conv_b, vg + (long)h * 16384 * 1536);
    }
    hipLaunchKernelGGL(HIP_KERNEL_NAME(gemm_kernel<0>), dim3(6, 256), dim3(256), 0, stream,
                       vg, w_op, 1536, 768, outb,
                       (const float*)nullptr, (const bf16s*)nullptr, la, (float*)nullptr);
    hipLaunchKernelGGL(HIP_KERNEL_NAME(gemm_kernel<0>), dim3(6, 256), dim3(256), 0, stream,
                       outb, w_wr, 768, 768, vb,
                       (const float*)nullptr, (const bf16s*)nullptr, la, (float*)nullptr);
    hipLaunchKernelGGL(HIP_KERNEL_NAME(transpose_kernel<1, 0>), dim3(12, 64, 8), dim3(256), 0, stream,
                       outb, oTs, decay);
    hipLaunchKernelGGL(HIP_KERNEL_NAME(transpose_kernel<0, 1>), dim3(12, 64, 8), dim3(256), 0, stream,
                       vb, vTs, decay);
    hipLaunchKernelGGL(wstate_kernel, dim3(36, 8), dim3(256), 0, stream,
                       vTs, oTs, Wst, decay);
    hipLaunchKernelGGL(pmat_kernel, dim3(64, 4, 8), dim3(256), 0, stream,
                       outb, Pm, decay);          // clobbers vb+oTs (both dead)
    hipLaunchKernelGGL(reads_kernel, dim3(48, 4, 8), dim3(256), 0, stream,
                       outb, Wst, Pm, vTs, readsb, decay);
    hipLaunchKernelGGL(HIP_KERNEL_NAME(gemm_kernel<1>), dim3(6, 256), dim3(256), 0, stream,
                       readsb, w_rd, 768, 768, (bf16s*)nullptr,
                       x, outb, la, (float*)d_out);
}

// Round 4
// 888.453 us; speedup vs baseline: 1.1789x; 1.0572x over previous
//
#include <hip/hip_runtime.h>
#include <stdint.h>

// ----------------------------------------------------------------------------
// HebbianLayer on MI355X (gfx950).
// B=8, T=4096, D=768, d_inner=1536, reference CHUNK=64.
// R3: scan re-chunked to C=1024 -> 3 parallel GEMM kernels (wstate/pmat/reads).
// R4: conv rewritten as sliding-window streaming kernel.
// R5: 256x256 8-phase GEMM engine — REGRESSED. Reverted.
// R6: 128^2 engine + XCD-chunked gemm swizzle + reads heavy-first (939 us).
// R7: XCD L2 pinning for the scan kernels (gridDim.x = 8 = batch -> linear%8
// == b, each batch's 3-6 MB working set pinned to one XCD's 4 MB L2).
// R8: resubmit of R7 (container infra failure, no counters); pmat triangular
// decode switched from sqrtf to exact integer form (defense in depth).
// ----------------------------------------------------------------------------

typedef short bf16s;                                            // raw bf16 bits
typedef __attribute__((ext_vector_type(8))) short short8;       // 4 VGPR mfma frag
typedef __attribute__((ext_vector_type(4))) float f32x4;        // mfma acc

#define DEVINL __device__ __forceinline__

DEVINL float bf2f(short s) {
    union { unsigned u; float f; } v; v.u = ((unsigned)(unsigned short)s) << 16; return v.f;
}
DEVINL short f2bf(float f) {
    union { float f; unsigned u; } v; v.f = f;
    unsigned r = v.u + 0x7fffu + ((v.u >> 16) & 1u);            // RNE
    return (short)(r >> 16);
}

// async global->LDS, 16B per lane. LDS dest must be wave-uniform.
DEVINL void glds16(void* lds, const void* g) {
    __builtin_amdgcn_global_load_lds(
        (const __attribute__((address_space(1))) void*)g,
        (__attribute__((address_space(3))) void*)lds, 16, 0, 0);
}

// Stage a 128-row x 64-col bf16 tile. g must be pre-offset by
// sr*gstride + sf*8 where sr=tid>>3, sf=(tid&7)^(sr&7) (XOR slot swizzle).
DEVINL void stage128(bf16s* lds, const bf16s* g, long gstride, int wave) {
#pragma unroll
    for (int p = 0; p < 4; ++p)
        glds16(lds + p * 2048 + wave * 512, g + (long)p * 32 * gstride);
}

// Read an A/B fragment from a swizzled 64-col tile.
DEVINL short8 fragr(const bf16s* t, int row, int kk, int q) {
    int f = kk * 4 + q;
    return *(const short8*)(t + row * 64 + ((f ^ (row & 7)) * 8));
}

#define MFMA(a, b, c) __builtin_amdgcn_mfma_f32_16x16x32_bf16((a), (b), (c), 0, 0, 0)

// ---------------------------------------------------------------------------
// K0: weight casts (fp32 -> bf16). w_pg = [proj_w ; gate_w] rows (3072x768).
// ---------------------------------------------------------------------------
__global__ __launch_bounds__(256) void cast_w_kernel(
    const float* __restrict__ proj, const float* __restrict__ gate,
    const float* __restrict__ op, const float* __restrict__ wr, const float* __restrict__ rd,
    bf16s* __restrict__ w_pg, bf16s* __restrict__ w_op, bf16s* __restrict__ w_wr,
    bf16s* __restrict__ w_rd) {
    long i = (long)blockIdx.x * 256 + threadIdx.x;
    if (i < 1179648)        w_pg[i] = f2bf(proj[i]);
    else if (i < 2359296)   w_pg[i] = f2bf(gate[i - 1179648]);
    else if (i < 3538944)   w_op[i - 2359296] = f2bf(op[i - 2359296]);
    else if (i < 4128768)   w_wr[i - 3538944] = f2bf(wr[i - 3538944]);
    else if (i < 4718592)   w_rd[i - 4128768] = f2bf(rd[i - 4128768]);
}

// ---------------------------------------------------------------------------
// K1: RMSNorm + cast. One block per row (768 elems).
// ---------------------------------------------------------------------------
__global__ __launch_bounds__(256) void rmsnorm_kernel(
    const float* __restrict__ x, const float* __restrict__ w, bf16s* __restrict__ xn) {
    long row = blockIdx.x;
    const float* xr = x + row * 768;
    int tid = threadIdx.x;
    float v0 = xr[tid], v1 = xr[tid + 256], v2 = xr[tid + 512];
    float ss = v0 * v0 + v1 * v1 + v2 * v2;
#pragma unroll
    for (int off = 32; off; off >>= 1) ss += __shfl_down(ss, off);
    __shared__ float p[4];
    if ((tid & 63) == 0) p[tid >> 6] = ss;
    __syncthreads();
    float tot = p[0] + p[1] + p[2] + p[3];
    float s = rsqrtf(tot * (1.0f / 768.0f) + 1e-5f);
    bf16s* o = xn + row * 768;
    o[tid]       = f2bf(v0 * s * w[tid]);
    o[tid + 256] = f2bf(v1 * s * w[tid + 256]);
    o[tid + 512] = f2bf(v2 * s * w[tid + 512]);
}

// ---------------------------------------------------------------------------
// GEMM: C[M,N] = A[M,K] @ B[N,K]^T. 128x128 tile, BK=64, 4 waves 2x2.
// MODE 0: store bf16.   MODE 1: d_out = x + bf2f(outres) + exp(la)*acc (f32).
// XCD-chunked block swizzle (R6): each XCD gets a contiguous logical range.
// ---------------------------------------------------------------------------
template <int MODE>
__global__ __launch_bounds__(256, 2) void gemm_kernel(
    const bf16s* __restrict__ A, const bf16s* __restrict__ B, int K, int N,
    bf16s* __restrict__ Cb, const float* __restrict__ xres,
    const bf16s* __restrict__ outres, const float* __restrict__ p_la,
    float* __restrict__ Cout) {
    __shared__ bf16s sA[128 * 64];
    __shared__ bf16s sB[128 * 64];
    const int tid = threadIdx.x;
    const int wave = tid >> 6, lane = tid & 63;
    const int wm = wave >> 1, wn = wave & 1;
    const int ln15 = lane & 15, q = lane >> 4;
    // XCD-chunked swizzle (bijective; nb % 8 == 0 for all launches)
    const int nbx = gridDim.x;
    const int nb = nbx * gridDim.y;
    const int l = blockIdx.y * nbx + blockIdx.x;
    const int L = (l & 7) * (nb >> 3) + (l >> 3);
    const int bx = L % nbx, by = L / nbx;
    const long m0 = (long)by * 128, n0 = (long)bx * 128;
    const int sr = tid >> 3;
    const int sf = (tid & 7) ^ (sr & 7);
    const bf16s* gA = A + (m0 + sr) * K + sf * 8;
    const bf16s* gB = B + (n0 + sr) * K + sf * 8;
    f32x4 acc[4][4] = {};
    const int nkt = K >> 6;
    for (int kt = 0; kt < nkt; ++kt) {
        __syncthreads();
        stage128(sA, gA, K, wave);
        stage128(sB, gB, K, wave);
        gA += 64; gB += 64;
        asm volatile("s_waitcnt vmcnt(0)" ::: "memory");
        __syncthreads();
#pragma unroll
        for (int kk = 0; kk < 2; ++kk) {
            short8 af[4], bf_[4];
#pragma unroll
            for (int i = 0; i < 4; ++i) af[i] = fragr(sA, wm * 64 + i * 16 + ln15, kk, q);
#pragma unroll
            for (int j = 0; j < 4; ++j) bf_[j] = fragr(sB, wn * 64 + j * 16 + ln15, kk, q);
#pragma unroll
            for (int i = 0; i < 4; ++i)
#pragma unroll
                for (int j = 0; j < 4; ++j) acc[i][j] = MFMA(af[i], bf_[j], acc[i][j]);
        }
    }
    float alpha = 0.f;
    if (MODE == 1) alpha = __expf(p_la[0]);
#pragma unroll
    for (int i = 0; i < 4; ++i)
#pragma unroll
        for (int j = 0; j < 4; ++j) {
            long mb = m0 + wm * 64 + i * 16 + q * 4;
            long nc = n0 + wn * 64 + j * 16 + ln15;
#pragma unroll
            for (int e = 0; e < 4; ++e) {
                long m = mb + e;
                float v = acc[i][j][e];
                if (MODE == 0) {
                    Cb[m * N + nc] = f2bf(v);
                } else {
                    long idx = m * 768 + nc;
                    Cout[idx] = xres[idx] + bf2f(outres[idx]) + alpha * v;
                }
            }
        }
}

// ---------------------------------------------------------------------------
// K3: depthwise causal conv(4) + bias + SiLU, gated by SiLU(gate).
// ---------------------------------------------------------------------------
__global__ __launch_bounds__(192) void conv_kernel(
    const bf16s* __restrict__ pg, const float* __restrict__ cw,
    const float* __restrict__ cb, bf16s* __restrict__ vg) {
    const int e0 = threadIdx.x * 8;
    const long l0 = (long)blockIdx.x * 16;
    float w0[8], w1[8], w2[8], w3[8], bias[8];
#pragma unroll
    for (int i = 0; i < 8; ++i) {
        const float* wc = cw + (e0 + i) * 4;
        w0[i] = wc[0]; w1[i] = wc[1]; w2[i] = wc[2]; w3[i] = wc[3];
        bias[i] = cb[e0 + i];
    }
    const bf16s* base = pg + l0 * 3072 + e0;
    short8 h0, h1, h2;
    if ((l0 & 4095) == 0) {
        short8 z = {0, 0, 0, 0, 0, 0, 0, 0};
        h0 = z; h1 = z; h2 = z;
    } else {
        h0 = *(const short8*)(base - 3 * 3072);
        h1 = *(const short8*)(base - 2 * 3072);
        h2 = *(const short8*)(base - 1 * 3072);
    }
    short8 cur = *(const short8*)base;
    short8 g8  = *(const short8*)(base + 1536);
    bf16s* out = vg + l0 * 1536 + e0;
#pragma unroll 4
    for (int t = 0; t < 16; ++t) {
        short8 ncur, ng;
        if (t < 15) {                       // prefetch next row
            ncur = *(const short8*)(base + 3072);
            ng   = *(const short8*)(base + 3072 + 1536);
        }
        short8 o;
#pragma unroll
        for (int i = 0; i < 8; ++i) {
            float vv = bias[i] + bf2f(h0[i]) * w0[i] + bf2f(h1[i]) * w1[i]
                     + bf2f(h2[i]) * w2[i] + bf2f(cur[i]) * w3[i];
            float sv = vv / (1.0f + __expf(-vv));
            float gg = bf2f(g8[i]);
            o[i] = f2bf(sv * (gg / (1.0f + __expf(-gg))));
        }
        *(short8*)out = o;
        h0 = h1; h1 = h2; h2 = cur;
        cur = ncur; g8 = ng;
        base += 3072; out += 1536;
    }
}

// ---------------------------------------------------------------------------
// K5: transpose [b][t][e] -> [b][e][t], optional shift (t -> t-1, zero fill)
// and optional gw scale gamma^(1023 - t%1024). bf16 -> bf16.
// ---------------------------------------------------------------------------
template <int SHIFT, int GW>
__global__ __launch_bounds__(256) void transpose_kernel(
    const bf16s* __restrict__ src, bf16s* __restrict__ dst,
    const float* __restrict__ p_decay) {
    int b = blockIdx.z;
    long t0 = (long)blockIdx.y * 64, e0 = (long)blockIdx.x * 64;
    __shared__ bf16s tile[64][72];
    int tid = threadIdx.x;
    int r = tid >> 2, cs = (tid & 3) * 16;
    long tsrc = t0 + r - SHIFT;
    if (tsrc >= 0) {
        const bf16s* s = src + ((long)b * 4096 + tsrc) * 768 + e0 + cs;
        short8 v0 = *(const short8*)s;
        short8 v1 = *(const short8*)(s + 8);
        if (GW) {
            float gm = 1.0f / (1.0f + __expf(-p_decay[0]));
            float gwf = exp2f(__log2f(gm) * (float)(1023 - (int)(tsrc & 1023)));
#pragma unroll
            for (int i = 0; i < 8; ++i) {
                tile[r][cs + i]     = f2bf(bf2f(v0[i]) * gwf);
                tile[r][cs + 8 + i] = f2bf(bf2f(v1[i]) * gwf);
            }
        } else {
#pragma unroll
            for (int i = 0; i < 8; ++i) {
                tile[r][cs + i]     = v0[i];
                tile[r][cs + 8 + i] = v1[i];
            }
        }
    } else {
#pragma unroll
        for (int i = 0; i < 16; ++i) tile[r][cs + i] = 0;
    }
    __syncthreads();
    int er = tid >> 2, ts = (tid & 3) * 16;
    short8 a, bb;
#pragma unroll
    for (int i = 0; i < 8; ++i) a[i] = tile[ts + i][er];
#pragma unroll
    for (int i = 0; i < 8; ++i) bb[i] = tile[ts + 8 + i][er];
    bf16s* d = dst + ((long)b * 768 + e0 + er) * 4096 + t0 + ts;
    *(short8*)d = a;
    *(short8*)(d + 8) = bb;
}

// ---------------------------------------------------------------------------
// K6: W-state kernel. C=1024, Nc=4. Block owns one 128x128 tile of W[vd][kd]
// for one b. R7: grid (8, 36), x = b -> all 36 tiles of a batch on one XCD,
// streaming the same vTs/oTs K-columns in lockstep through its L2.
// ---------------------------------------------------------------------------
__global__ __launch_bounds__(256, 2) void wstate_kernel(
    const bf16s* __restrict__ vTs, const bf16s* __restrict__ oTs,
    bf16s* __restrict__ Wst, const float* __restrict__ p_decay) {
    __shared__ bf16s sA[128 * 64];
    __shared__ bf16s sB[128 * 64];
    const int b = blockIdx.x;                    // linear%8 == b -> XCD pin
    const int ti = blockIdx.y % 6, tj = blockIdx.y / 6;
    const int tid = threadIdx.x;
    const int wave = tid >> 6, lane = tid & 63;
    const int wm = wave >> 1, wn = wave & 1;
    const int ln15 = lane & 15, q = lane >> 4;
    const int sr = tid >> 3;
    const int sf = (tid & 7) ^ (sr & 7);
    const bf16s* gA = vTs + ((long)b * 768 + ti * 128 + sr) * 4096 + sf * 8;
    const bf16s* gB = oTs + ((long)b * 768 + tj * 128 + sr) * 4096 + sf * 8;
    const float gm = 1.0f / (1.0f + __expf(-p_decay[0]));
    const float gC = exp2f(__log2f(gm) * 1024.0f);
    f32x4 acc[4][4] = {};
    for (int jc = 0; jc < 4; ++jc) {
        bf16s* Wj = Wst + ((long)(b * 4 + jc)) * 768 * 768;
#pragma unroll
        for (int i = 0; i < 4; ++i)
#pragma unroll
            for (int jj = 0; jj < 4; ++jj) {
                long mb = ti * 128 + wm * 64 + i * 16 + q * 4;
                long nc = tj * 128 + wn * 64 + jj * 16 + ln15;
#pragma unroll
                for (int e = 0; e < 4; ++e) {
                    Wj[(mb + e) * 768 + nc] = f2bf(acc[i][jj][e]);
                    acc[i][jj][e] *= gC;
                }
            }
        for (int kt = 0; kt < 16; ++kt) {
            __syncthreads();
            stage128(sA, gA, 4096, wave);
            stage128(sB, gB, 4096, wave);
            gA += 64; gB += 64;
            asm volatile("s_waitcnt vmcnt(0)" ::: "memory");
            __syncthreads();
#pragma unroll
            for (int kk = 0; kk < 2; ++kk) {
                short8 af[4], bf_[4];
#pragma unroll
                for (int i = 0; i < 4; ++i) af[i] = fragr(sA, wm * 64 + i * 16 + ln15, kk, q);
#pragma unroll
                for (int j = 0; j < 4; ++j) bf_[j] = fragr(sB, wn * 64 + j * 16 + ln15, kk, q);
#pragma unroll
                for (int i = 0; i < 4; ++i)
#pragma unroll
                    for (int j = 0; j < 4; ++j) acc[i][j] = MFMA(af[i], bf_[j], acc[i][j]);
            }
        }
    }
}

// ---------------------------------------------------------------------------
// K7: P'[b,j][c][c'] = bf16( (r_c . k_c') * gamma^(c-1024) * (c>c') ).
// R7: grid (8, 144), x = b (XCD pin), y = j*36 + lower-tri tile id
// (direct enumeration, no dead blocks). R8: exact integer tri decode.
// ---------------------------------------------------------------------------
__global__ __launch_bounds__(256, 2) void pmat_kernel(
    const bf16s* __restrict__ outb, bf16s* __restrict__ P,
    const float* __restrict__ p_decay) {
    const int b = blockIdx.x;                    // linear%8 == b -> XCD pin
    const int j = blockIdx.y / 36;
    const int t = blockIdx.y % 36;               // lower-tri tile id
    // exact integer triangular decode: largest ci with ci*(ci+1)/2 <= t
    int ci = 0;
#pragma unroll
    for (int c = 1; c < 8; ++c) ci += (c * (c + 1) / 2 <= t) ? 1 : 0;
    const int cj = t - ci * (ci + 1) / 2;
    const bool fix = (j == 0 && cj == 0);
    __shared__ bf16s sA[128 * 64];
    __shared__ bf16s sB[128 * 64];
    const int tid = threadIdx.x;
    const int wave = tid >> 6, lane = tid & 63;
    const int wm = wave >> 1, wn = wave & 1;
    const int ln15 = lane & 15, q = lane >> 4;
    const int sr = tid >> 3;
    const int sf = (tid & 7) ^ (sr & 7);
    const bf16s* gA = outb + ((long)b * 4096 + j * 1024 + ci * 128 + sr) * 768 + sf * 8;
    const bf16s* gB = outb + ((long)b * 4096 + j * 1024 + cj * 128 + sr - 1) * 768 + sf * 8;
    f32x4 acc[4][4] = {};
    for (int kt = 0; kt < 12; ++kt) {
        __syncthreads();
        stage128(sA, gA, 768, wave);
        stage128(sB, gB, 768, wave);
        gA += 64; gB += 64;
        asm volatile("s_waitcnt vmcnt(0)" ::: "memory");
        __syncthreads();
        if (fix) {                         // B row 0 is global t=-1 -> zero
            if (tid < 8) { short8 zz = {0,0,0,0,0,0,0,0}; ((short8*)sB)[tid] = zz; }
            __syncthreads();
        }
#pragma unroll
        for (int kk = 0; kk < 2; ++kk) {
            short8 af[4], bf_[4];
#pragma unroll
            for (int i = 0; i < 4; ++i) af[i] = fragr(sA, wm * 64 + i * 16 + ln15, kk, q);
#pragma unroll
            for (int jj = 0; jj < 4; ++jj) bf_[jj] = fragr(sB, wn * 64 + jj * 16 + ln15, kk, q);
#pragma unroll
            for (int i = 0; i < 4; ++i)
#pragma unroll
                for (int jj = 0; jj < 4; ++jj) acc[i][jj] = MFMA(af[i], bf_[jj], acc[i][jj]);
        }
    }
    const float lg = __log2f(1.0f / (1.0f + __expf(-p_decay[0])));
    bf16s* Pb = P + ((long)(b * 4 + j) << 20);
#pragma unroll
    for (int i = 0; i < 4; ++i)
#pragma unroll
        for (int jj = 0; jj < 4; ++jj) {
            int cb_ = ci * 128 + wm * 64 + i * 16 + q * 4;
            int cp  = cj * 128 + wn * 64 + jj * 16 + ln15;
#pragma unroll
            for (int e = 0; e < 4; ++e) {
                int c = cb_ + e;
                float val = (c > cp) ? acc[i][jj][e] * exp2f(lg * (float)(c - 1024)) : 0.0f;
                Pb[(long)c * 1024 + cp] = f2bf(val);
            }
        }
}

// ---------------------------------------------------------------------------
// K8: reads[c, vd] = gamma^(c%1024) * (r_c @ Wst[b,j]^T)   [skip for j==0]
//                  + P'[b,j] @ vTs^T                        (K limited to c'<=c)
// R7: grid (8, 192), x = b (XCD pin). y = p*48 + (7-ci)*6 + vi:
//   p -> j=(p+1)&3 (light j=0 last); ci descending (superset-first);
//   vi inner (6 same-ci blocks share Pm A-panels).
// ---------------------------------------------------------------------------
__global__ __launch_bounds__(256, 2) void reads_kernel(
    const bf16s* __restrict__ outb, const bf16s* __restrict__ Wst,
    const bf16s* __restrict__ Pm, const bf16s* __restrict__ vTs,
    bf16s* __restrict__ readsb, const float* __restrict__ p_decay) {
    const int b = blockIdx.x;                    // linear%8 == b -> XCD pin
    const int p = blockIdx.y / 48;
    const int inner = blockIdx.y % 48;
    const int j = (p + 1) & 3;                   // 1,2,3,0
    const int ci = 7 - inner / 6;
    const int vi = inner % 6;
    __shared__ bf16s sA[128 * 64];
    __shared__ bf16s sB[128 * 64];
    const int tid = threadIdx.x;
    const int wave = tid >> 6, lane = tid & 63;
    const int wm = wave >> 1, wn = wave & 1;
    const int ln15 = lane & 15, q = lane >> 4;
    const int sr = tid >> 3;
    const int sf = (tid & 7) ^ (sr & 7);
    const float lg = __log2f(1.0f / (1.0f + __expf(-p_decay[0])));
    f32x4 acc[4][4] = {};
    if (j > 0) {
        const bf16s* gA = outb + ((long)b * 4096 + j * 1024 + ci * 128 + sr) * 768 + sf * 8;
        const bf16s* gB = Wst + ((long)(b * 4 + j) * 768 + vi * 128 + sr) * 768 + sf * 8;
        for (int kt = 0; kt < 12; ++kt) {
            __syncthreads();
            stage128(sA, gA, 768, wave);
            stage128(sB, gB, 768, wave);
            gA += 64; gB += 64;
            asm volatile("s_waitcnt vmcnt(0)" ::: "memory");
            __syncthreads();
#pragma unroll
            for (int kk = 0; kk < 2; ++kk) {
                short8 af[4], bf_[4];
#pragma unroll
                for (int i = 0; i < 4; ++i) af[i] = fragr(sA, wm * 64 + i * 16 + ln15, kk, q);
#pragma unroll
                for (int jj = 0; jj < 4; ++jj) bf_[jj] = fragr(sB, wn * 64 + jj * 16 + ln15, kk, q);
#pragma unroll
                for (int i = 0; i < 4; ++i)
#pragma unroll
                    for (int jj = 0; jj < 4; ++jj) acc[i][jj] = MFMA(af[i], bf_[jj], acc[i][jj]);
            }
        }
#pragma unroll
        for (int i = 0; i < 4; ++i) {
            int cb_ = ci * 128 + wm * 64 + i * 16 + q * 4;
#pragma unroll
            for (int e = 0; e < 4; ++e) {
                float s = exp2f(lg * (float)(cb_ + e));
#pragma unroll
                for (int jj = 0; jj < 4; ++jj) acc[i][jj][e] *= s;
            }
        }
    }
    {
        const bf16s* gA = Pm + ((long)(b * 4 + j) << 20) + (long)(ci * 128 + sr) * 1024 + sf * 8;
        const bf16s* gB = vTs + ((long)b * 768 + vi * 128 + sr) * 4096 + j * 1024 + sf * 8;
        const int nkt = 2 * (ci + 1);
        for (int kt = 0; kt < nkt; ++kt) {
            __syncthreads();
            stage128(sA, gA, 1024, wave);
            stage128(sB, gB, 4096, wave);
            gA += 64; gB += 64;
            asm volatile("s_waitcnt vmcnt(0)" ::: "memory");
            __syncthreads();
#pragma unroll
            for (int kk = 0; kk < 2; ++kk) {
                short8 af[4], bf_[4];
#pragma unroll
                for (int i = 0; i < 4; ++i) af[i] = fragr(sA, wm * 64 + i * 16 + ln15, kk, q);
#pragma unroll
                for (int jj = 0; jj < 4; ++jj) bf_[jj] = fragr(sB, wn * 64 + jj * 16 + ln15, kk, q);
#pragma unroll
                for (int i = 0; i < 4; ++i)
#pragma unroll
                    for (int jj = 0; jj < 4; ++jj) acc[i][jj] = MFMA(af[i], bf_[jj], acc[i][jj]);
            }
        }
    }
#pragma unroll
    for (int i = 0; i < 4; ++i)
#pragma unroll
        for (int jj = 0; jj < 4; ++jj) {
            long tb = (long)j * 1024 + ci * 128 + wm * 64 + i * 16 + q * 4;
            long nc = vi * 128 + wn * 64 + jj * 16 + ln15;
#pragma unroll
            for (int e = 0; e < 4; ++e)
                readsb[((long)b * 4096 + tb + e) * 768 + nc] = f2bf(acc[i][jj][e]);
        }
}

// ---------------------------------------------------------------------------
extern "C" void kernel_launch(void* const* d_in, const int* in_sizes, int n_in,
                              void* d_out, int out_size, void* d_ws, size_t ws_size,
                              hipStream_t stream) {
    (void)in_sizes; (void)n_in; (void)out_size;
    const float* x      = (const float*)d_in[0];
    const float* norm_w = (const float*)d_in[1];
    const float* proj_w = (const float*)d_in[2];
    const float* gate_w = (const float*)d_in[3];
    const float* conv_w = (const float*)d_in[4];
    const float* conv_b = (const float*)d_in[5];
    const float* op_w   = (const float*)d_in[6];
    const float* wr_w   = (const float*)d_in[7];
    const float* rd_w   = (const float*)d_in[8];
    const float* decay  = (const float*)d_in[9];
    const float* la     = (const float*)d_in[10];

    // -------- workspace layout (liveness overlays), ~312.4 MB total --------
    char* ws = (char*)d_ws;
    size_t off = 0;
    auto alloc = [&](size_t bytes) { void* p = ws + off; off += (bytes + 255) & ~(size_t)255; return p; };
    bf16s* w_pg = (bf16s*)alloc(3072l * 768 * 2);          // 4.7 MB
    bf16s* w_op = (bf16s*)alloc(768l * 1536 * 2);          // 2.4 MB
    bf16s* w_wr = (bf16s*)alloc(768l * 768 * 2);           // 1.2 MB
    bf16s* w_rd = (bf16s*)alloc(768l * 768 * 2);           // 1.2 MB
    bf16s* RA   = (bf16s*)alloc(32768l * 768 * 2);         // 50.3 MB: xn | vTs
    bf16s* RB   = (bf16s*)alloc(2 * 32768l * 768 * 2);     // 100.7 MB: pg | vb+oTs | P'
    bf16s* RC   = (bf16s*)alloc(2 * 32768l * 768 * 2);     // 100.7 MB: vg | Wst+reads
    bf16s* RE   = (bf16s*)alloc(32768l * 768 * 2);         // 50.3 MB: outb
    if (ws_size < off) return;   // diagnostic guard: fail clean, don't fault

    bf16s* xn    = RA;
    bf16s* vTs   = RA;
    bf16s* pgH   = RB;                     // 16384 x 3072 (one M-half)
    bf16s* vb    = RB;                     // [0:50.3 MB]
    bf16s* oTs   = RB + 25165824;          // [50.3:100.7 MB]
    bf16s* Pm    = RB;                     // 67.1 MB (after vb & oTs are dead)
    bf16s* vg    = RC;                     // 32768 x 1536
    bf16s* Wst   = RC;                     // 37.75 MB (after vg dead)
    bf16s* readsb= RC + 18874368;          // [37.75:88.1 MB]
    bf16s* outb  = RE;

    hipLaunchKernelGGL(cast_w_kernel, dim3(18432), dim3(256), 0, stream,
                       proj_w, gate_w, op_w, wr_w, rd_w, w_pg, w_op, w_wr, w_rd);
    hipLaunchKernelGGL(rmsnorm_kernel, dim3(32768), dim3(256), 0, stream, x, norm_w, xn);
    // proj+gate GEMM + conv, split at the batch-4 boundary (no conv halo)
    for (int h = 0; h < 2; ++h) {
        hipLaunchKernelGGL(HIP_KERNEL_NAME(gemm_kernel<0>), dim3(24, 128), dim3(256), 0, stream,
                           xn + (long)h * 16384 * 768, w_pg, 768, 3072, pgH,
                           (const float*)nullptr, (const bf16s*)nullptr, la, (float*)nullptr);
        hipLaunchKernelGGL(conv_kernel, dim3(1024), dim3(192), 0, stream,
                           pgH, conv_w, conv_b, vg + (long)h * 16384 * 1536);
    }
    hipLaunchKernelGGL(HIP_KERNEL_NAME(gemm_kernel<0>), dim3(6, 256), dim3(256), 0, stream,
                       vg, w_op, 1536, 768, outb,
                       (const float*)nullptr, (const bf16s*)nullptr, la, (float*)nullptr);
    hipLaunchKernelGGL(HIP_KERNEL_NAME(gemm_kernel<0>), dim3(6, 256), dim3(256), 0, stream,
                       outb, w_wr, 768, 768, vb,
                       (const float*)nullptr, (const bf16s*)nullptr, la, (float*)nullptr);
    hipLaunchKernelGGL(HIP_KERNEL_NAME(transpose_kernel<1, 0>), dim3(12, 64, 8), dim3(256), 0, stream,
                       outb, oTs, decay);
    hipLaunchKernelGGL(HIP_KERNEL_NAME(transpose_kernel<0, 1>), dim3(12, 64, 8), dim3(256), 0, stream,
                       vb, vTs, decay);
    hipLaunchKernelGGL(wstate_kernel, dim3(8, 36), dim3(256), 0, stream,
                       vTs, oTs, Wst, decay);
    hipLaunchKernelGGL(pmat_kernel, dim3(8, 144), dim3(256), 0, stream,
                       outb, Pm, decay);          // clobbers vb+oTs (both dead)
    hipLaunchKernelGGL(reads_kernel, dim3(8, 192), dim3(256), 0, stream,
                       outb, Wst, Pm, vTs, readsb, decay);
    hipLaunchKernelGGL(HIP_KERNEL_NAME(gemm_kernel<1>), dim3(6, 256), dim3(256), 0, stream,
                       readsb, w_rd, 768, 768, (bf16s*)nullptr,
                       x, outb, la, (float*)d_out);
}

// Round 5
// 887.166 us; speedup vs baseline: 1.1806x; 1.0015x over previous
//
#include <hip/hip_runtime.h>
#include <stdint.h>

// ----------------------------------------------------------------------------
// HebbianLayer on MI355X (gfx950).
// B=8, T=4096, D=768, d_inner=1536, reference CHUNK=64.
// R3: scan re-chunked to C=1024 -> 3 parallel GEMM kernels (wstate/pmat/reads).
// R4: conv rewritten as sliding-window streaming kernel.
// R5: 256x256 8-phase engine everywhere — REGRESSED on N=768 tails. Reverted.
// R6: 128^2 engine + XCD-chunked gemm swizzle (939).
// R7/R8: XCD L2 pinning for scan kernels (gridDim.x=8=batch) (888).
// R9: (a) gemm8 (256^2 8-phase) for the pg GEMMs only — grid 768 blocks =
// exactly 3 rounds; R5 arithmetic shows pg8 ~80 vs 92 us. N=768 GEMMs stay
// on the 128^2 engine. (b) write-GEMM MODE 3: fused transpose + gw-scale
// epilogue writes vTs directly (drops transpose<0,1> and vb traffic).
// ----------------------------------------------------------------------------

typedef short bf16s;                                            // raw bf16 bits
typedef __attribute__((ext_vector_type(8))) short short8;       // 4 VGPR mfma frag
typedef __attribute__((ext_vector_type(4))) short short4v;      // 8B LDS store
typedef __attribute__((ext_vector_type(4))) float f32x4;        // mfma acc

#define DEVINL __device__ __forceinline__

DEVINL float bf2f(short s) {
    union { unsigned u; float f; } v; v.u = ((unsigned)(unsigned short)s) << 16; return v.f;
}
DEVINL short f2bf(float f) {
    union { float f; unsigned u; } v; v.f = f;
    unsigned r = v.u + 0x7fffu + ((v.u >> 16) & 1u);            // RNE
    return (short)(r >> 16);
}

// async global->LDS, 16B per lane. LDS dest must be wave-uniform.
DEVINL void glds16(void* lds, const void* g) {
    __builtin_amdgcn_global_load_lds(
        (const __attribute__((address_space(1))) void*)g,
        (__attribute__((address_space(3))) void*)lds, 16, 0, 0);
}

// Stage a 128-row x 64-col bf16 tile with 256 threads (4 waves). g must be
// pre-offset by sr*gstride + sf*8 where sr=tid>>3, sf=(tid&7)^(sr&7).
DEVINL void stage128(bf16s* lds, const bf16s* g, long gstride, int wave) {
#pragma unroll
    for (int p = 0; p < 4; ++p)
        glds16(lds + p * 2048 + wave * 512, g + (long)p * 32 * gstride);
}

// Same tile staged by 512 threads (8 waves): 2 x 16B per thread.
DEVINL void stage_half512(bf16s* lds, const bf16s* g, long gstride, int wave) {
#pragma unroll
    for (int p = 0; p < 2; ++p)
        glds16(lds + p * 4096 + wave * 512, g + (long)p * 64 * gstride);
}

// Read an A/B fragment from a swizzled 64-col tile.
DEVINL short8 fragr(const bf16s* t, int row, int kk, int q) {
    int f = kk * 4 + q;
    return *(const short8*)(t + row * 64 + ((f ^ (row & 7)) * 8));
}

#define MFMA(a, b, c) __builtin_amdgcn_mfma_f32_16x16x32_bf16((a), (b), (c), 0, 0, 0)

// ---------------------------------------------------------------------------
// K0: weight casts (fp32 -> bf16). w_pg = [proj_w ; gate_w] rows (3072x768).
// ---------------------------------------------------------------------------
__global__ __launch_bounds__(256) void cast_w_kernel(
    const float* __restrict__ proj, const float* __restrict__ gate,
    const float* __restrict__ op, const float* __restrict__ wr, const float* __restrict__ rd,
    bf16s* __restrict__ w_pg, bf16s* __restrict__ w_op, bf16s* __restrict__ w_wr,
    bf16s* __restrict__ w_rd) {
    long i = (long)blockIdx.x * 256 + threadIdx.x;
    if (i < 1179648)        w_pg[i] = f2bf(proj[i]);
    else if (i < 2359296)   w_pg[i] = f2bf(gate[i - 1179648]);
    else if (i < 3538944)   w_op[i - 2359296] = f2bf(op[i - 2359296]);
    else if (i < 4128768)   w_wr[i - 3538944] = f2bf(wr[i - 3538944]);
    else if (i < 4718592)   w_rd[i - 4128768] = f2bf(rd[i - 4128768]);
}

// ---------------------------------------------------------------------------
// K1: RMSNorm + cast. One block per row (768 elems).
// ---------------------------------------------------------------------------
__global__ __launch_bounds__(256) void rmsnorm_kernel(
    const float* __restrict__ x, const float* __restrict__ w, bf16s* __restrict__ xn) {
    long row = blockIdx.x;
    const float* xr = x + row * 768;
    int tid = threadIdx.x;
    float v0 = xr[tid], v1 = xr[tid + 256], v2 = xr[tid + 512];
    float ss = v0 * v0 + v1 * v1 + v2 * v2;
#pragma unroll
    for (int off = 32; off; off >>= 1) ss += __shfl_down(ss, off);
    __shared__ float p[4];
    if ((tid & 63) == 0) p[tid >> 6] = ss;
    __syncthreads();
    float tot = p[0] + p[1] + p[2] + p[3];
    float s = rsqrtf(tot * (1.0f / 768.0f) + 1e-5f);
    bf16s* o = xn + row * 768;
    o[tid]       = f2bf(v0 * s * w[tid]);
    o[tid + 256] = f2bf(v1 * s * w[tid + 256]);
    o[tid + 512] = f2bf(v2 * s * w[tid + 512]);
}

// ---------------------------------------------------------------------------
// GEMM: C[M,N] = A[M,K] @ B[N,K]^T. 128x128 tile, BK=64, 4 waves 2x2.
// MODE 0: store bf16.   MODE 1: d_out = x + bf2f(outres) + exp(la)*acc (f32).
// MODE 3: fused write-GEMM: store nothing to Cb; instead transpose the C-tile
// in LDS and write Tdst[b][e][t] = f2bf(bf2f(f2bf(acc)) * gamma^(1023-t%1024))
// (bit-identical to old vb + transpose<0,1> path).
// XCD-chunked block swizzle (R6): each XCD gets a contiguous logical range.
// ---------------------------------------------------------------------------
template <int MODE>
__global__ __launch_bounds__(256, 2) void gemm_kernel(
    const bf16s* __restrict__ A, const bf16s* __restrict__ B, int K, int N,
    bf16s* __restrict__ Cb, const float* __restrict__ xres,
    const bf16s* __restrict__ outres, const float* __restrict__ p_la,
    float* __restrict__ Cout, const float* __restrict__ p_decay,
    bf16s* __restrict__ Tdst) {
    __shared__ bf16s smem[128 * 136];            // staging (16K shorts) | tbuf
    bf16s* sA = smem;
    bf16s* sB = smem + 8192;
    const int tid = threadIdx.x;
    const int wave = tid >> 6, lane = tid & 63;
    const int wm = wave >> 1, wn = wave & 1;
    const int ln15 = lane & 15, q = lane >> 4;
    // XCD-chunked swizzle (bijective; nb % 8 == 0 for all launches)
    const int nbx = gridDim.x;
    const int nb = nbx * gridDim.y;
    const int l = blockIdx.y * nbx + blockIdx.x;
    const int L = (l & 7) * (nb >> 3) + (l >> 3);
    const int bx = L % nbx, by = L / nbx;
    const long m0 = (long)by * 128, n0 = (long)bx * 128;
    const int sr = tid >> 3;
    const int sf = (tid & 7) ^ (sr & 7);
    const bf16s* gA = A + (m0 + sr) * K + sf * 8;
    const bf16s* gB = B + (n0 + sr) * K + sf * 8;
    f32x4 acc[4][4] = {};
    const int nkt = K >> 6;
    for (int kt = 0; kt < nkt; ++kt) {
        __syncthreads();
        stage128(sA, gA, K, wave);
        stage128(sB, gB, K, wave);
        gA += 64; gB += 64;
        asm volatile("s_waitcnt vmcnt(0)" ::: "memory");
        __syncthreads();
#pragma unroll
        for (int kk = 0; kk < 2; ++kk) {
            short8 af[4], bf_[4];
#pragma unroll
            for (int i = 0; i < 4; ++i) af[i] = fragr(sA, wm * 64 + i * 16 + ln15, kk, q);
#pragma unroll
            for (int j = 0; j < 4; ++j) bf_[j] = fragr(sB, wn * 64 + j * 16 + ln15, kk, q);
#pragma unroll
            for (int i = 0; i < 4; ++i)
#pragma unroll
                for (int j = 0; j < 4; ++j) acc[i][j] = MFMA(af[i], bf_[j], acc[i][j]);
        }
    }
    if (MODE == 3) {
        // --- fused transpose + gw-scale epilogue -> Tdst (vTs layout) ---
        __syncthreads();                         // staging LDS now dead
        bf16s* tbuf = smem;                      // [128][136]
#pragma unroll
        for (int i = 0; i < 4; ++i)
#pragma unroll
            for (int j = 0; j < 4; ++j) {
                int nn = wn * 64 + j * 16 + ln15;
                int mm = wm * 64 + i * 16 + q * 4;
                short4v t4;
#pragma unroll
                for (int e = 0; e < 4; ++e) t4[e] = f2bf(acc[i][j][e]);
                *(short4v*)(tbuf + nn * 136 + mm) = t4;
            }
        __syncthreads();
        const float lg = __log2f(1.0f / (1.0f + __expf(-p_decay[0])));
        const long b = m0 >> 12;
        const int tb = (int)(m0 & 4095);
#pragma unroll
        for (int it = 0; it < 4; ++it) {
            int chunk = it * 256 + tid;
            int nn = chunk >> 3, mc = (chunk & 7) * 16;
            short8 v0 = *(const short8*)(tbuf + nn * 136 + mc);
            short8 v1 = *(const short8*)(tbuf + nn * 136 + mc + 8);
            short8 o0, o1;
#pragma unroll
            for (int k2 = 0; k2 < 8; ++k2) {
                float g0 = exp2f(lg * (float)(1023 - ((tb + mc + k2) & 1023)));
                float g1 = exp2f(lg * (float)(1023 - ((tb + mc + 8 + k2) & 1023)));
                o0[k2] = f2bf(bf2f(v0[k2]) * g0);
                o1[k2] = f2bf(bf2f(v1[k2]) * g1);
            }
            bf16s* d = Tdst + (b * 768 + n0 + nn) * 4096 + tb + mc;
            *(short8*)d = o0;
            *(short8*)(d + 8) = o1;
        }
        return;
    }
    float alpha = 0.f;
    if (MODE == 1) alpha = __expf(p_la[0]);
#pragma unroll
    for (int i = 0; i < 4; ++i)
#pragma unroll
        for (int j = 0; j < 4; ++j) {
            long mb = m0 + wm * 64 + i * 16 + q * 4;
            long nc = n0 + wn * 64 + j * 16 + ln15;
#pragma unroll
            for (int e = 0; e < 4; ++e) {
                long m = mb + e;
                float v = acc[i][j][e];
                if (MODE == 0) {
                    Cb[m * N + nc] = f2bf(v);
                } else {
                    long idx = m * 768 + nc;
                    Cout[idx] = xres[idx] + bf2f(outres[idx]) + alpha * v;
                }
            }
        }
}

// ---------------------------------------------------------------------------
// GEMM8: C[M,N] = A[M,K] @ B[N,K]^T. 256x256 tile, BK=64, 8 waves (2Mx4N),
// 8-phase double-buffered schedule, counted vmcnt(4). Verified bit-identical
// in R5. Used ONLY for the pg GEMMs (grid 768 blocks = 3 exact CU rounds).
// ---------------------------------------------------------------------------
#define P_MID()                                                   \
    asm volatile("" ::: "memory");                                \
    __builtin_amdgcn_s_barrier();                                 \
    asm volatile("s_waitcnt lgkmcnt(0)" ::: "memory");            \
    __builtin_amdgcn_sched_barrier(0);                            \
    __builtin_amdgcn_s_setprio(1)

#define P_END()                                                   \
    __builtin_amdgcn_s_setprio(0);                                \
    asm volatile("" ::: "memory");                                \
    __builtin_amdgcn_s_barrier();                                 \
    asm volatile("" ::: "memory")

#define P_END_VM()                                                \
    __builtin_amdgcn_s_setprio(0);                                \
    asm volatile("s_waitcnt vmcnt(4)" ::: "memory");              \
    asm volatile("" ::: "memory");                                \
    __builtin_amdgcn_s_barrier();                                 \
    asm volatile("" ::: "memory")

#define RD_A(dst, s, kk)                                          \
    _Pragma("unroll")                                             \
    for (int m = 0; m < 8; ++m) dst[m] = fragr(&sA8[s][wm][0], m * 16 + ln15, kk, q)

#define RD_B(dst, s, kk)                                          \
    _Pragma("unroll")                                             \
    for (int n = 0; n < 4; ++n) dst[n] = fragr(&sB8[s][bh][0], (wn & 1) * 64 + n * 16 + ln15, kk, q)

#define Q_MFMA(af, bfr, nlo)                                      \
    _Pragma("unroll")                                             \
    for (int m = 0; m < 8; ++m) {                                 \
        acc[m][nlo]     = MFMA(af[m], bfr[nlo],     acc[m][nlo]);     \
        acc[m][nlo + 1] = MFMA(af[m], bfr[nlo + 1], acc[m][nlo + 1]); \
    }

__global__ __launch_bounds__(512, 2) void gemm8_kernel(
    const bf16s* __restrict__ A, const bf16s* __restrict__ B, int K, int N,
    bf16s* __restrict__ Cb) {
    __shared__ bf16s sA8[2][2][8192];    // [slot][half: M 0-127 / 128-255]
    __shared__ bf16s sB8[2][2][8192];    // [slot][half: N 0-127 / 128-255]
    const int tid = threadIdx.x;
    const int wave = tid >> 6, lane = tid & 63;
    const int wm = wave >> 2, wn = wave & 3;     // 2 M-waves x 4 N-waves
    const int bh = wn >> 1;                      // which B half this wave reads
    const int ln15 = lane & 15, q = lane >> 4;
    const long m0 = (long)blockIdx.y * 256, n0 = (long)blockIdx.x * 256;
    const int sr = tid >> 3;                     // 0..63
    const int sf = (tid & 7) ^ (sr & 7);
    const bf16s* pA0 = A + (m0 + sr) * K + sf * 8;
    const bf16s* pA1 = A + (m0 + 128 + sr) * K + sf * 8;
    const bf16s* pB0 = B + (n0 + sr) * K + sf * 8;
    const bf16s* pB1 = B + (n0 + 128 + sr) * K + sf * 8;
    const int NKT = K >> 6, NI = NKT >> 1;

    // prologue
    stage_half512(&sA8[0][0][0], pA0, K, wave);
    stage_half512(&sA8[0][1][0], pA1, K, wave);
    stage_half512(&sB8[0][0][0], pB0, K, wave);
    stage_half512(&sB8[0][1][0], pB1, K, wave);
    stage_half512(&sA8[1][0][0], pA0 + 64, K, wave);
    stage_half512(&sA8[1][1][0], pA1 + 64, K, wave);
    asm volatile("s_waitcnt vmcnt(4)" ::: "memory");
    asm volatile("" ::: "memory");
    __builtin_amdgcn_s_barrier();
    asm volatile("" ::: "memory");

    f32x4 acc[8][4] = {};
    short8 a0[8], a1[8], b0[4], b1[4];

    for (int it = 0; it < NI; ++it) {
        const long o1 = (long)(2 * it + 1) * 64;
        int t2 = 2 * it + 2; if (t2 > NKT - 1) t2 = NKT - 1;   // clamped dummy
        int t3 = 2 * it + 3; if (t3 > NKT - 1) t3 = NKT - 1;   // (keeps vmcnt
        const long o2 = (long)t2 * 64, o3 = (long)t3 * 64;     //  counts exact)
        // ---- phases 1-4: compute K-tile 2it from slot 0 ----
        RD_A(a0, 0, 0); RD_B(b0, 0, 0);
        stage_half512(&sB8[1][0][0], pB0 + o1, K, wave);
        P_MID(); Q_MFMA(a0, b0, 0); P_END();
        RD_A(a1, 0, 1);
        stage_half512(&sB8[1][1][0], pB1 + o1, K, wave);
        P_MID(); Q_MFMA(a0, b0, 2); P_END();
        RD_B(b1, 0, 1);
        stage_half512(&sA8[0][0][0], pA0 + o2, K, wave);
        P_MID(); Q_MFMA(a1, b1, 0); P_END();
        stage_half512(&sA8[0][1][0], pA1 + o2, K, wave);
        P_MID(); Q_MFMA(a1, b1, 2); P_END_VM();
        // ---- phases 5-8: compute K-tile 2it+1 from slot 1 ----
        RD_A(a0, 1, 0); RD_B(b0, 1, 0);
        stage_half512(&sB8[0][0][0], pB0 + o2, K, wave);
        P_MID(); Q_MFMA(a0, b0, 0); P_END();
        RD_A(a1, 1, 1);
        stage_half512(&sB8[0][1][0], pB1 + o2, K, wave);
        P_MID(); Q_MFMA(a0, b0, 2); P_END();
        RD_B(b1, 1, 1);
        stage_half512(&sA8[1][0][0], pA0 + o3, K, wave);
        P_MID(); Q_MFMA(a1, b1, 0); P_END();
        stage_half512(&sA8[1][1][0], pA1 + o3, K, wave);
        P_MID(); Q_MFMA(a1, b1, 2); P_END_VM();
    }
    asm volatile("s_waitcnt vmcnt(0)" ::: "memory");

#pragma unroll
    for (int m = 0; m < 8; ++m)
#pragma unroll
        for (int n = 0; n < 4; ++n) {
            long mb = m0 + wm * 128 + m * 16 + q * 4;
            long nc = n0 + wn * 64 + n * 16 + ln15;
#pragma unroll
            for (int e = 0; e < 4; ++e)
                Cb[(mb + e) * N + nc] = f2bf(acc[m][n][e]);
        }
}

// ---------------------------------------------------------------------------
// K3: depthwise causal conv(4) + bias + SiLU, gated by SiLU(gate).
// ---------------------------------------------------------------------------
__global__ __launch_bounds__(192) void conv_kernel(
    const bf16s* __restrict__ pg, const float* __restrict__ cw,
    const float* __restrict__ cb, bf16s* __restrict__ vg) {
    const int e0 = threadIdx.x * 8;
    const long l0 = (long)blockIdx.x * 16;
    float w0[8], w1[8], w2[8], w3[8], bias[8];
#pragma unroll
    for (int i = 0; i < 8; ++i) {
        const float* wc = cw + (e0 + i) * 4;
        w0[i] = wc[0]; w1[i] = wc[1]; w2[i] = wc[2]; w3[i] = wc[3];
        bias[i] = cb[e0 + i];
    }
    const bf16s* base = pg + l0 * 3072 + e0;
    short8 h0, h1, h2;
    if ((l0 & 4095) == 0) {
        short8 z = {0, 0, 0, 0, 0, 0, 0, 0};
        h0 = z; h1 = z; h2 = z;
    } else {
        h0 = *(const short8*)(base - 3 * 3072);
        h1 = *(const short8*)(base - 2 * 3072);
        h2 = *(const short8*)(base - 1 * 3072);
    }
    short8 cur = *(const short8*)base;
    short8 g8  = *(const short8*)(base + 1536);
    bf16s* out = vg + l0 * 1536 + e0;
#pragma unroll 4
    for (int t = 0; t < 16; ++t) {
        short8 ncur, ng;
        if (t < 15) {                       // prefetch next row
            ncur = *(const short8*)(base + 3072);
            ng   = *(const short8*)(base + 3072 + 1536);
        }
        short8 o;
#pragma unroll
        for (int i = 0; i < 8; ++i) {
            float vv = bias[i] + bf2f(h0[i]) * w0[i] + bf2f(h1[i]) * w1[i]
                     + bf2f(h2[i]) * w2[i] + bf2f(cur[i]) * w3[i];
            float sv = vv / (1.0f + __expf(-vv));
            float gg = bf2f(g8[i]);
            o[i] = f2bf(sv * (gg / (1.0f + __expf(-gg))));
        }
        *(short8*)out = o;
        h0 = h1; h1 = h2; h2 = cur;
        cur = ncur; g8 = ng;
        base += 3072; out += 1536;
    }
}

// ---------------------------------------------------------------------------
// K5: transpose [b][t][e] -> [b][e][t], optional shift (t -> t-1, zero fill).
// Only the SHIFT=1,GW=0 instance remains (outb -> oTs).
// ---------------------------------------------------------------------------
template <int SHIFT, int GW>
__global__ __launch_bounds__(256) void transpose_kernel(
    const bf16s* __restrict__ src, bf16s* __restrict__ dst,
    const float* __restrict__ p_decay) {
    int b = blockIdx.z;
    long t0 = (long)blockIdx.y * 64, e0 = (long)blockIdx.x * 64;
    __shared__ bf16s tile[64][72];
    int tid = threadIdx.x;
    int r = tid >> 2, cs = (tid & 3) * 16;
    long tsrc = t0 + r - SHIFT;
    if (tsrc >= 0) {
        const bf16s* s = src + ((long)b * 4096 + tsrc) * 768 + e0 + cs;
        short8 v0 = *(const short8*)s;
        short8 v1 = *(const short8*)(s + 8);
        if (GW) {
            float gm = 1.0f / (1.0f + __expf(-p_decay[0]));
            float gwf = exp2f(__log2f(gm) * (float)(1023 - (int)(tsrc & 1023)));
#pragma unroll
            for (int i = 0; i < 8; ++i) {
                tile[r][cs + i]     = f2bf(bf2f(v0[i]) * gwf);
                tile[r][cs + 8 + i] = f2bf(bf2f(v1[i]) * gwf);
            }
        } else {
#pragma unroll
            for (int i = 0; i < 8; ++i) {
                tile[r][cs + i]     = v0[i];
                tile[r][cs + 8 + i] = v1[i];
            }
        }
    } else {
#pragma unroll
        for (int i = 0; i < 16; ++i) tile[r][cs + i] = 0;
    }
    __syncthreads();
    int er = tid >> 2, ts = (tid & 3) * 16;
    short8 a, bb;
#pragma unroll
    for (int i = 0; i < 8; ++i) a[i] = tile[ts + i][er];
#pragma unroll
    for (int i = 0; i < 8; ++i) bb[i] = tile[ts + 8 + i][er];
    bf16s* d = dst + ((long)b * 768 + e0 + er) * 4096 + t0 + ts;
    *(short8*)d = a;
    *(short8*)(d + 8) = bb;
}

// ---------------------------------------------------------------------------
// K6: W-state kernel. grid (8, 36), x = b -> XCD pin (R7).
// ---------------------------------------------------------------------------
__global__ __launch_bounds__(256, 2) void wstate_kernel(
    const bf16s* __restrict__ vTs, const bf16s* __restrict__ oTs,
    bf16s* __restrict__ Wst, const float* __restrict__ p_decay) {
    __shared__ bf16s sA[128 * 64];
    __shared__ bf16s sB[128 * 64];
    const int b = blockIdx.x;                    // linear%8 == b -> XCD pin
    const int ti = blockIdx.y % 6, tj = blockIdx.y / 6;
    const int tid = threadIdx.x;
    const int wave = tid >> 6, lane = tid & 63;
    const int wm = wave >> 1, wn = wave & 1;
    const int ln15 = lane & 15, q = lane >> 4;
    const int sr = tid >> 3;
    const int sf = (tid & 7) ^ (sr & 7);
    const bf16s* gA = vTs + ((long)b * 768 + ti * 128 + sr) * 4096 + sf * 8;
    const bf16s* gB = oTs + ((long)b * 768 + tj * 128 + sr) * 4096 + sf * 8;
    const float gm = 1.0f / (1.0f + __expf(-p_decay[0]));
    const float gC = exp2f(__log2f(gm) * 1024.0f);
    f32x4 acc[4][4] = {};
    for (int jc = 0; jc < 4; ++jc) {
        bf16s* Wj = Wst + ((long)(b * 4 + jc)) * 768 * 768;
#pragma unroll
        for (int i = 0; i < 4; ++i)
#pragma unroll
            for (int jj = 0; jj < 4; ++jj) {
                long mb = ti * 128 + wm * 64 + i * 16 + q * 4;
                long nc = tj * 128 + wn * 64 + jj * 16 + ln15;
#pragma unroll
                for (int e = 0; e < 4; ++e) {
                    Wj[(mb + e) * 768 + nc] = f2bf(acc[i][jj][e]);
                    acc[i][jj][e] *= gC;
                }
            }
        for (int kt = 0; kt < 16; ++kt) {
            __syncthreads();
            stage128(sA, gA, 4096, wave);
            stage128(sB, gB, 4096, wave);
            gA += 64; gB += 64;
            asm volatile("s_waitcnt vmcnt(0)" ::: "memory");
            __syncthreads();
#pragma unroll
            for (int kk = 0; kk < 2; ++kk) {
                short8 af[4], bf_[4];
#pragma unroll
                for (int i = 0; i < 4; ++i) af[i] = fragr(sA, wm * 64 + i * 16 + ln15, kk, q);
#pragma unroll
                for (int j = 0; j < 4; ++j) bf_[j] = fragr(sB, wn * 64 + j * 16 + ln15, kk, q);
#pragma unroll
                for (int i = 0; i < 4; ++i)
#pragma unroll
                    for (int j = 0; j < 4; ++j) acc[i][j] = MFMA(af[i], bf_[j], acc[i][j]);
            }
        }
    }
}

// ---------------------------------------------------------------------------
// K7: P'[b,j][c][c'] = bf16( (r_c . k_c') * gamma^(c-1024) * (c>c') ).
// grid (8, 144), x = b (XCD pin), y = j*36 + lower-tri tile id.
// ---------------------------------------------------------------------------
__global__ __launch_bounds__(256, 2) void pmat_kernel(
    const bf16s* __restrict__ outb, bf16s* __restrict__ P,
    const float* __restrict__ p_decay) {
    const int b = blockIdx.x;                    // linear%8 == b -> XCD pin
    const int j = blockIdx.y / 36;
    const int t = blockIdx.y % 36;               // lower-tri tile id
    int ci = 0;
#pragma unroll
    for (int c = 1; c < 8; ++c) ci += (c * (c + 1) / 2 <= t) ? 1 : 0;
    const int cj = t - ci * (ci + 1) / 2;
    const bool fix = (j == 0 && cj == 0);
    __shared__ bf16s sA[128 * 64];
    __shared__ bf16s sB[128 * 64];
    const int tid = threadIdx.x;
    const int wave = tid >> 6, lane = tid & 63;
    const int wm = wave >> 1, wn = wave & 1;
    const int ln15 = lane & 15, q = lane >> 4;
    const int sr = tid >> 3;
    const int sf = (tid & 7) ^ (sr & 7);
    const bf16s* gA = outb + ((long)b * 4096 + j * 1024 + ci * 128 + sr) * 768 + sf * 8;
    const bf16s* gB = outb + ((long)b * 4096 + j * 1024 + cj * 128 + sr - 1) * 768 + sf * 8;
    f32x4 acc[4][4] = {};
    for (int kt = 0; kt < 12; ++kt) {
        __syncthreads();
        stage128(sA, gA, 768, wave);
        stage128(sB, gB, 768, wave);
        gA += 64; gB += 64;
        asm volatile("s_waitcnt vmcnt(0)" ::: "memory");
        __syncthreads();
        if (fix) {                         // B row 0 is global t=-1 -> zero
            if (tid < 8) { short8 zz = {0,0,0,0,0,0,0,0}; ((short8*)sB)[tid] = zz; }
            __syncthreads();
        }
#pragma unroll
        for (int kk = 0; kk < 2; ++kk) {
            short8 af[4], bf_[4];
#pragma unroll
            for (int i = 0; i < 4; ++i) af[i] = fragr(sA, wm * 64 + i * 16 + ln15, kk, q);
#pragma unroll
            for (int jj = 0; jj < 4; ++jj) bf_[jj] = fragr(sB, wn * 64 + jj * 16 + ln15, kk, q);
#pragma unroll
            for (int i = 0; i < 4; ++i)
#pragma unroll
                for (int jj = 0; jj < 4; ++jj) acc[i][jj] = MFMA(af[i], bf_[jj], acc[i][jj]);
        }
    }
    const float lg = __log2f(1.0f / (1.0f + __expf(-p_decay[0])));
    bf16s* Pb = P + ((long)(b * 4 + j) << 20);
#pragma unroll
    for (int i = 0; i < 4; ++i)
#pragma unroll
        for (int jj = 0; jj < 4; ++jj) {
            int cb_ = ci * 128 + wm * 64 + i * 16 + q * 4;
            int cp  = cj * 128 + wn * 64 + jj * 16 + ln15;
#pragma unroll
            for (int e = 0; e < 4; ++e) {
                int c = cb_ + e;
                float val = (c > cp) ? acc[i][jj][e] * exp2f(lg * (float)(c - 1024)) : 0.0f;
                Pb[(long)c * 1024 + cp] = f2bf(val);
            }
        }
}

// ---------------------------------------------------------------------------
// K8: reads kernel. grid (8, 192), x = b (XCD pin), superset-first order (R7).
// ---------------------------------------------------------------------------
__global__ __launch_bounds__(256, 2) void reads_kernel(
    const bf16s* __restrict__ outb, const bf16s* __restrict__ Wst,
    const bf16s* __restrict__ Pm, const bf16s* __restrict__ vTs,
    bf16s* __restrict__ readsb, const float* __restrict__ p_decay) {
    const int b = blockIdx.x;                    // linear%8 == b -> XCD pin
    const int p = blockIdx.y / 48;
    const int inner = blockIdx.y % 48;
    const int j = (p + 1) & 3;                   // 1,2,3,0
    const int ci = 7 - inner / 6;
    const int vi = inner % 6;
    __shared__ bf16s sA[128 * 64];
    __shared__ bf16s sB[128 * 64];
    const int tid = threadIdx.x;
    const int wave = tid >> 6, lane = tid & 63;
    const int wm = wave >> 1, wn = wave & 1;
    const int ln15 = lane & 15, q = lane >> 4;
    const int sr = tid >> 3;
    const int sf = (tid & 7) ^ (sr & 7);
    const float lg = __log2f(1.0f / (1.0f + __expf(-p_decay[0])));
    f32x4 acc[4][4] = {};
    if (j > 0) {
        const bf16s* gA = outb + ((long)b * 4096 + j * 1024 + ci * 128 + sr) * 768 + sf * 8;
        const bf16s* gB = Wst + ((long)(b * 4 + j) * 768 + vi * 128 + sr) * 768 + sf * 8;
        for (int kt = 0; kt < 12; ++kt) {
            __syncthreads();
            stage128(sA, gA, 768, wave);
            stage128(sB, gB, 768, wave);
            gA += 64; gB += 64;
            asm volatile("s_waitcnt vmcnt(0)" ::: "memory");
            __syncthreads();
#pragma unroll
            for (int kk = 0; kk < 2; ++kk) {
                short8 af[4], bf_[4];
#pragma unroll
                for (int i = 0; i < 4; ++i) af[i] = fragr(sA, wm * 64 + i * 16 + ln15, kk, q);
#pragma unroll
                for (int jj = 0; jj < 4; ++jj) bf_[jj] = fragr(sB, wn * 64 + jj * 16 + ln15, kk, q);
#pragma unroll
                for (int i = 0; i < 4; ++i)
#pragma unroll
                    for (int jj = 0; jj < 4; ++jj) acc[i][jj] = MFMA(af[i], bf_[jj], acc[i][jj]);
            }
        }
#pragma unroll
        for (int i = 0; i < 4; ++i) {
            int cb_ = ci * 128 + wm * 64 + i * 16 + q * 4;
#pragma unroll
            for (int e = 0; e < 4; ++e) {
                float s = exp2f(lg * (float)(cb_ + e));
#pragma unroll
                for (int jj = 0; jj < 4; ++jj) acc[i][jj][e] *= s;
            }
        }
    }
    {
        const bf16s* gA = Pm + ((long)(b * 4 + j) << 20) + (long)(ci * 128 + sr) * 1024 + sf * 8;
        const bf16s* gB = vTs + ((long)b * 768 + vi * 128 + sr) * 4096 + j * 1024 + sf * 8;
        const int nkt = 2 * (ci + 1);
        for (int kt = 0; kt < nkt; ++kt) {
            __syncthreads();
            stage128(sA, gA, 1024, wave);
            stage128(sB, gB, 4096, wave);
            gA += 64; gB += 64;
            asm volatile("s_waitcnt vmcnt(0)" ::: "memory");
            __syncthreads();
#pragma unroll
            for (int kk = 0; kk < 2; ++kk) {
                short8 af[4], bf_[4];
#pragma unroll
                for (int i = 0; i < 4; ++i) af[i] = fragr(sA, wm * 64 + i * 16 + ln15, kk, q);
#pragma unroll
                for (int jj = 0; jj < 4; ++jj) bf_[jj] = fragr(sB, wn * 64 + jj * 16 + ln15, kk, q);
#pragma unroll
                for (int i = 0; i < 4; ++i)
#pragma unroll
                    for (int jj = 0; jj < 4; ++jj) acc[i][jj] = MFMA(af[i], bf_[jj], acc[i][jj]);
            }
        }
    }
#pragma unroll
    for (int i = 0; i < 4; ++i)
#pragma unroll
        for (int jj = 0; jj < 4; ++jj) {
            long tb = (long)j * 1024 + ci * 128 + wm * 64 + i * 16 + q * 4;
            long nc = vi * 128 + wn * 64 + jj * 16 + ln15;
#pragma unroll
            for (int e = 0; e < 4; ++e)
                readsb[((long)b * 4096 + tb + e) * 768 + nc] = f2bf(acc[i][jj][e]);
        }
}

// ---------------------------------------------------------------------------
extern "C" void kernel_launch(void* const* d_in, const int* in_sizes, int n_in,
                              void* d_out, int out_size, void* d_ws, size_t ws_size,
                              hipStream_t stream) {
    (void)in_sizes; (void)n_in; (void)out_size;
    const float* x      = (const float*)d_in[0];
    const float* norm_w = (const float*)d_in[1];
    const float* proj_w = (const float*)d_in[2];
    const float* gate_w = (const float*)d_in[3];
    const float* conv_w = (const float*)d_in[4];
    const float* conv_b = (const float*)d_in[5];
    const float* op_w   = (const float*)d_in[6];
    const float* wr_w   = (const float*)d_in[7];
    const float* rd_w   = (const float*)d_in[8];
    const float* decay  = (const float*)d_in[9];
    const float* la     = (const float*)d_in[10];

    // -------- workspace layout (liveness overlays), ~312.4 MB total --------
    char* ws = (char*)d_ws;
    size_t off = 0;
    auto alloc = [&](size_t bytes) { void* p = ws + off; off += (bytes + 255) & ~(size_t)255; return p; };
    bf16s* w_pg = (bf16s*)alloc(3072l * 768 * 2);          // 4.7 MB
    bf16s* w_op = (bf16s*)alloc(768l * 1536 * 2);          // 2.4 MB
    bf16s* w_wr = (bf16s*)alloc(768l * 768 * 2);           // 1.2 MB
    bf16s* w_rd = (bf16s*)alloc(768l * 768 * 2);           // 1.2 MB
    bf16s* RA   = (bf16s*)alloc(32768l * 768 * 2);         // 50.3 MB: xn | vTs
    bf16s* RB   = (bf16s*)alloc(2 * 32768l * 768 * 2);     // 100.7 MB: pg | oTs | P'
    bf16s* RC   = (bf16s*)alloc(2 * 32768l * 768 * 2);     // 100.7 MB: vg | Wst+reads
    bf16s* RE   = (bf16s*)alloc(32768l * 768 * 2);         // 50.3 MB: outb
    if (ws_size < off) return;   // diagnostic guard: fail clean, don't fault

    bf16s* xn    = RA;
    bf16s* vTs   = RA;                     // written by MODE 3 write-GEMM
    bf16s* pgH   = RB;                     // 16384 x 3072 (one M-half)
    bf16s* oTs   = RB + 25165824;          // [50.3:100.7 MB]
    bf16s* Pm    = RB;                     // 67.1 MB (after oTs is dead)
    bf16s* vg    = RC;                     // 32768 x 1536
    bf16s* Wst   = RC;                     // 37.75 MB (after vg dead)
    bf16s* readsb= RC + 18874368;          // [37.75:88.1 MB]
    bf16s* outb  = RE;

    hipLaunchKernelGGL(cast_w_kernel, dim3(18432), dim3(256), 0, stream,
                       proj_w, gate_w, op_w, wr_w, rd_w, w_pg, w_op, w_wr, w_rd);
    hipLaunchKernelGGL(rmsnorm_kernel, dim3(32768), dim3(256), 0, stream, x, norm_w, xn);
    // proj+gate GEMM (256^2 8-phase engine; 768 blocks = 3 exact rounds) + conv
    for (int h = 0; h < 2; ++h) {
        hipLaunchKernelGGL(gemm8_kernel, dim3(12, 64), dim3(512), 0, stream,
                           xn + (long)h * 16384 * 768, w_pg, 768, 3072, pgH);
        hipLaunchKernelGGL(conv_kernel, dim3(1024), dim3(192), 0, stream,
                           pgH, conv_w, conv_b, vg + (long)h * 16384 * 1536);
    }
    hipLaunchKernelGGL(HIP_KERNEL_NAME(gemm_kernel<0>), dim3(6, 256), dim3(256), 0, stream,
                       vg, w_op, 1536, 768, outb,
                       (const float*)nullptr, (const bf16s*)nullptr, la, (float*)nullptr,
                       (const float*)nullptr, (bf16s*)nullptr);
    // write-GEMM with fused transpose + gw-scale -> vTs (replaces vb + transpose<0,1>)
    hipLaunchKernelGGL(HIP_KERNEL_NAME(gemm_kernel<3>), dim3(6, 256), dim3(256), 0, stream,
                       outb, w_wr, 768, 768, (bf16s*)nullptr,
                       (const float*)nullptr, (const bf16s*)nullptr, la, (float*)nullptr,
                       decay, vTs);
    hipLaunchKernelGGL(HIP_KERNEL_NAME(transpose_kernel<1, 0>), dim3(12, 64, 8), dim3(256), 0, stream,
                       outb, oTs, decay);
    hipLaunchKernelGGL(wstate_kernel, dim3(8, 36), dim3(256), 0, stream,
                       vTs, oTs, Wst, decay);
    hipLaunchKernelGGL(pmat_kernel, dim3(8, 144), dim3(256), 0, stream,
                       outb, Pm, decay);          // clobbers pg/oTs region (dead)
    hipLaunchKernelGGL(reads_kernel, dim3(8, 192), dim3(256), 0, stream,
                       outb, Wst, Pm, vTs, readsb, decay);
    hipLaunchKernelGGL(HIP_KERNEL_NAME(gemm_kernel<1>), dim3(6, 256), dim3(256), 0, stream,
                       readsb, w_rd, 768, 768, (bf16s*)nullptr,
                       x, outb, la, (float*)d_out,
                       (const float*)nullptr, (bf16s*)nullptr);
}